// Round 1
// baseline (1298.330 us; speedup 1.0000x reference)
//
#include <hip/hip_runtime.h>
#include <hip/hip_bf16.h>

#define N_NODES 100000
#define N_EDGES 1600000
#define NUM_GRAPHS 1000
#define SCAN_B 1024
#define SCAN_NB ((N_NODES + SCAN_B - 1) / SCAN_B)   // 98

// ---------------- utility ----------------
__global__ void zero_i32_kernel(int* __restrict__ p, int n) {
    int i = blockIdx.x * blockDim.x + threadIdx.x;
    if (i < n) p[i] = 0;
}

// ---------------- degree / dinv ----------------
__global__ void count_dst_kernel(const int* __restrict__ dst, int* __restrict__ cnt) {
    int e = blockIdx.x * blockDim.x + threadIdx.x;
    if (e < N_EDGES) atomicAdd(&cnt[dst[e]], 1);
}

__global__ void dinv_kernel(const int* __restrict__ cnt, float* __restrict__ dinv) {
    int i = blockIdx.x * blockDim.x + threadIdx.x;
    if (i < N_NODES) dinv[i] = rsqrtf((float)(cnt[i] + 1));  // +1 self loop; deg>=1 always
}

// ---------------- exclusive scan (row_ptr) ----------------
__global__ void scan1_kernel(const int* __restrict__ cnt, int* __restrict__ row_ptr,
                             int* __restrict__ blockSums) {
    __shared__ int sh[SCAN_B];
    int t = threadIdx.x;
    int i = blockIdx.x * SCAN_B + t;
    int v = (i < N_NODES) ? cnt[i] : 0;
    sh[t] = v;
    for (int off = 1; off < SCAN_B; off <<= 1) {
        __syncthreads();
        int add = (t >= off) ? sh[t - off] : 0;
        __syncthreads();
        sh[t] += add;
    }
    if (i < N_NODES) row_ptr[i] = sh[t] - v;          // local exclusive
    if (t == SCAN_B - 1) blockSums[blockIdx.x] = sh[t];
}

__global__ void scan2_kernel(int* __restrict__ blockSums, int* __restrict__ row_ptr) {
    if (threadIdx.x == 0 && blockIdx.x == 0) {
        int run = 0;
        for (int b = 0; b < SCAN_NB; ++b) { int s = blockSums[b]; blockSums[b] = run; run += s; }
        row_ptr[N_NODES] = run;   // == N_EDGES
    }
}

__global__ void scan3_kernel(int* __restrict__ row_ptr, const int* __restrict__ blockSums,
                             int* __restrict__ cursor) {
    int i = blockIdx.x * blockDim.x + threadIdx.x;
    if (i < N_NODES) {
        int v = row_ptr[i] + blockSums[i / SCAN_B];
        row_ptr[i] = v;
        cursor[i] = v;
    }
}

// ---------------- CSR fill ----------------
__global__ void fill_csr_kernel(const int* __restrict__ src, const int* __restrict__ dst,
                                int* __restrict__ cursor, int* __restrict__ csr_src) {
    int e = blockIdx.x * blockDim.x + threadIdx.x;
    if (e < N_EDGES) {
        int d = dst[e];
        int p = atomicAdd(&cursor[d], 1);
        csr_src[p] = src[e];
    }
}

// ---------------- GEMM1: x[N,256] @ W1[256,128] -> out[N,128] ----------------
__global__ __launch_bounds__(256) void gemm1_kernel(const float* __restrict__ x,
                                                    const float* __restrict__ W,
                                                    float* __restrict__ out) {
    const int f = threadIdx.x & 127;
    const int g = threadIdx.x >> 7;                  // 0..1
    const int row0 = blockIdx.x * 16 + g * 8;
    float acc[8];
#pragma unroll
    for (int r = 0; r < 8; ++r) acc[r] = 0.f;
    for (int k4 = 0; k4 < 64; ++k4) {
        float4 xv[8];
#pragma unroll
        for (int r = 0; r < 8; ++r)
            xv[r] = *(const float4*)&x[(size_t)(row0 + r) * 256 + k4 * 4];
#pragma unroll
        for (int j = 0; j < 4; ++j) {
            float w = W[(k4 * 4 + j) * 128 + f];
#pragma unroll
            for (int r = 0; r < 8; ++r) {
                float xs = (j == 0) ? xv[r].x : (j == 1) ? xv[r].y : (j == 2) ? xv[r].z : xv[r].w;
                acc[r] += xs * w;
            }
        }
    }
#pragma unroll
    for (int r = 0; r < 8; ++r)
        out[(size_t)(row0 + r) * 128 + f] = acc[r];
}

// ---------------- GEMM2: h[N,128] @ W2[128,64] -> out[N,64] ----------------
__global__ __launch_bounds__(256) void gemm2_kernel(const float* __restrict__ x,
                                                    const float* __restrict__ W,
                                                    float* __restrict__ out) {
    const int f = threadIdx.x & 63;
    const int g = threadIdx.x >> 6;                  // 0..3
    const int row0 = blockIdx.x * 32 + g * 8;
    float acc[8];
#pragma unroll
    for (int r = 0; r < 8; ++r) acc[r] = 0.f;
    for (int k4 = 0; k4 < 32; ++k4) {
        float4 xv[8];
#pragma unroll
        for (int r = 0; r < 8; ++r)
            xv[r] = *(const float4*)&x[(size_t)(row0 + r) * 128 + k4 * 4];
#pragma unroll
        for (int j = 0; j < 4; ++j) {
            float w = W[(k4 * 4 + j) * 64 + f];
#pragma unroll
            for (int r = 0; r < 8; ++r) {
                float xs = (j == 0) ? xv[r].x : (j == 1) ? xv[r].y : (j == 2) ? xv[r].z : xv[r].w;
                acc[r] += xs * w;
            }
        }
    }
#pragma unroll
    for (int r = 0; r < 8; ++r)
        out[(size_t)(row0 + r) * 64 + f] = acc[r];
}

// ---------------- agg1: out = Dh(A+I)Dh xw + b1, relu; F=128, one wave/node ----------------
__global__ __launch_bounds__(256) void agg1_kernel(const float* __restrict__ xw,
                                                   const int* __restrict__ csr_src,
                                                   const int* __restrict__ row_ptr,
                                                   const float* __restrict__ dinv,
                                                   const float* __restrict__ bias,
                                                   float* __restrict__ h) {
    const int node = blockIdx.x * 4 + (threadIdx.x >> 6);
    const int lane = threadIdx.x & 63;
    if (node >= N_NODES) return;
    const float di = dinv[node];
    float acc0 = xw[(size_t)node * 128 + lane] * di * di;        // self loop
    float acc1 = xw[(size_t)node * 128 + 64 + lane] * di * di;
    const int beg = row_ptr[node], end = row_ptr[node + 1];
    for (int e = beg; e < end; ++e) {
        int s = csr_src[e];
        float w = dinv[s] * di;
        acc0 += xw[(size_t)s * 128 + lane] * w;
        acc1 += xw[(size_t)s * 128 + 64 + lane] * w;
    }
    float v0 = acc0 + bias[lane];
    float v1 = acc1 + bias[64 + lane];
    h[(size_t)node * 128 + lane]      = v0 > 0.f ? v0 : 0.f;     // relu
    h[(size_t)node * 128 + 64 + lane] = v1 > 0.f ? v1 : 0.f;
}

// ---------------- agg2 + mean-pool: F=64, one wave/node, atomics into gsum ----------------
__global__ __launch_bounds__(256) void agg2_pool_kernel(const float* __restrict__ xw,
                                                        const int* __restrict__ csr_src,
                                                        const int* __restrict__ row_ptr,
                                                        const float* __restrict__ dinv,
                                                        const float* __restrict__ bias,
                                                        const int* __restrict__ batch,
                                                        float* __restrict__ gsum,
                                                        float* __restrict__ gcnt) {
    const int node = blockIdx.x * 4 + (threadIdx.x >> 6);
    const int lane = threadIdx.x & 63;
    if (node >= N_NODES) return;
    const float di = dinv[node];
    float acc = xw[(size_t)node * 64 + lane] * di * di;          // self loop
    const int beg = row_ptr[node], end = row_ptr[node + 1];
    for (int e = beg; e < end; ++e) {
        int s = csr_src[e];
        acc += xw[(size_t)s * 64 + lane] * (dinv[s] * di);
    }
    acc += bias[lane];
    int b = batch[node];
    atomicAdd(&gsum[b * 64 + lane], acc);
    if (lane == 0) atomicAdd(&gcnt[b], 1.0f);
}

// ---------------- head: mean -> fc -> log_softmax ----------------
__global__ void head_kernel(const float* __restrict__ gsum, const float* __restrict__ gcnt,
                            const float* __restrict__ fcW, const float* __restrict__ fcb,
                            float* __restrict__ out) {
    int g = blockIdx.x * blockDim.x + threadIdx.x;
    if (g >= NUM_GRAPHS) return;
    float c = gcnt[g];
    c = c > 1.f ? c : 1.f;
    float inv = 1.f / c;
    float logits[4];
#pragma unroll
    for (int j = 0; j < 4; ++j) logits[j] = fcb[j];
    for (int k = 0; k < 64; ++k) {
        float m = gsum[g * 64 + k] * inv;
#pragma unroll
        for (int j = 0; j < 4; ++j) logits[j] += m * fcW[k * 4 + j];
    }
    float mx = logits[0];
#pragma unroll
    for (int j = 1; j < 4; ++j) mx = logits[j] > mx ? logits[j] : mx;
    float s = 0.f;
#pragma unroll
    for (int j = 0; j < 4; ++j) s += expf(logits[j] - mx);
    float lse = mx + logf(s);
#pragma unroll
    for (int j = 0; j < 4; ++j) out[g * 4 + j] = logits[j] - lse;
}

extern "C" void kernel_launch(void* const* d_in, const int* in_sizes, int n_in,
                              void* d_out, int out_size, void* d_ws, size_t ws_size,
                              hipStream_t stream) {
    const float* x     = (const float*)d_in[0];
    const int*   ei    = (const int*)d_in[1];     // [2, E]
    const int*   batch = (const int*)d_in[2];
    const float* W1    = (const float*)d_in[3];
    const float* b1    = (const float*)d_in[4];
    const float* W2    = (const float*)d_in[5];
    const float* b2    = (const float*)d_in[6];
    const float* fcW   = (const float*)d_in[7];
    const float* fcb   = (const float*)d_in[8];
    float* out = (float*)d_out;

    const int* src = ei;
    const int* dst = ei + N_EDGES;

    // workspace carve-up (256B aligned)
    size_t o = 0;
    char* wsb = (char*)d_ws;
    auto take = [&](size_t bytes) -> void* {
        void* p = wsb + o;
        o += (bytes + 255) & ~(size_t)255;
        return p;
    };
    int*   cnt       = (int*)take((size_t)N_NODES * 4);
    float* dinv      = (float*)take((size_t)N_NODES * 4);
    int*   row_ptr   = (int*)take((size_t)(N_NODES + 1) * 4);
    int*   cursor    = (int*)take((size_t)N_NODES * 4);
    int*   csr_src   = (int*)take((size_t)N_EDGES * 4);
    int*   blockSums = (int*)take(1024);
    float* bufA      = (float*)take((size_t)N_NODES * 128 * 4);  // xw1, later xw2
    float* bufB      = (float*)take((size_t)N_NODES * 128 * 4);  // h1
    float* gsum      = (float*)take((size_t)NUM_GRAPHS * 64 * 4);
    float* gcnt      = (float*)take((size_t)NUM_GRAPHS * 4);
    (void)ws_size;

    const int TB = 256;

    // zero accumulators (ws is poisoned 0xAA before every call)
    zero_i32_kernel<<<(N_NODES + TB - 1) / TB, TB, 0, stream>>>(cnt, N_NODES);
    zero_i32_kernel<<<(NUM_GRAPHS * 64 + TB - 1) / TB, TB, 0, stream>>>((int*)gsum, NUM_GRAPHS * 64);
    zero_i32_kernel<<<(NUM_GRAPHS + TB - 1) / TB, TB, 0, stream>>>((int*)gcnt, NUM_GRAPHS);

    // degrees + dinv
    count_dst_kernel<<<(N_EDGES + TB - 1) / TB, TB, 0, stream>>>(dst, cnt);
    dinv_kernel<<<(N_NODES + TB - 1) / TB, TB, 0, stream>>>(cnt, dinv);

    // row_ptr = exclusive scan(cnt); cursor = row_ptr
    scan1_kernel<<<SCAN_NB, SCAN_B, 0, stream>>>(cnt, row_ptr, blockSums);
    scan2_kernel<<<1, 1, 0, stream>>>(blockSums, row_ptr);
    scan3_kernel<<<(N_NODES + TB - 1) / TB, TB, 0, stream>>>(row_ptr, blockSums, cursor);

    // CSR fill (dst-grouped src lists)
    fill_csr_kernel<<<(N_EDGES + TB - 1) / TB, TB, 0, stream>>>(src, dst, cursor, csr_src);

    // layer 1
    gemm1_kernel<<<N_NODES / 16, TB, 0, stream>>>(x, W1, bufA);
    agg1_kernel<<<N_NODES / 4, TB, 0, stream>>>(bufA, csr_src, row_ptr, dinv, b1, bufB);

    // layer 2 + pooling
    gemm2_kernel<<<N_NODES / 32, TB, 0, stream>>>(bufB, W2, bufA);
    agg2_pool_kernel<<<N_NODES / 4, TB, 0, stream>>>(bufA, csr_src, row_ptr, dinv, b2, batch,
                                                     gsum, gcnt);

    // head
    head_kernel<<<(NUM_GRAPHS + TB - 1) / TB, TB, 0, stream>>>(gsum, gcnt, fcW, fcb, out);
}

// Round 2
// 853.409 us; speedup vs baseline: 1.5213x; 1.5213x over previous
//
#include <hip/hip_runtime.h>
#include <hip/hip_bf16.h>

#define N_NODES 100000
#define N_EDGES 1600000
#define NUM_GRAPHS 1000
#define SCAN_B 1024
#define SCAN_NB ((N_NODES + SCAN_B - 1) / SCAN_B)   // 98

// ---------------- utility ----------------
__global__ void zero_i32_kernel(int* __restrict__ p, int n) {
    int i = blockIdx.x * blockDim.x + threadIdx.x;
    if (i < n) p[i] = 0;
}

// ---------------- degree / dinv ----------------
__global__ void count_dst_kernel(const int* __restrict__ dst, int* __restrict__ cnt) {
    int e = blockIdx.x * blockDim.x + threadIdx.x;
    if (e < N_EDGES) atomicAdd(&cnt[dst[e]], 1);
}

__global__ void dinv_kernel(const int* __restrict__ cnt, float* __restrict__ dinv) {
    int i = blockIdx.x * blockDim.x + threadIdx.x;
    if (i < N_NODES) dinv[i] = rsqrtf((float)(cnt[i] + 1));  // +1 self loop
}

// ---------------- exclusive scan (row_ptr) ----------------
__global__ void scan1_kernel(const int* __restrict__ cnt, int* __restrict__ row_ptr,
                             int* __restrict__ blockSums) {
    __shared__ int sh[SCAN_B];
    int t = threadIdx.x;
    int i = blockIdx.x * SCAN_B + t;
    int v = (i < N_NODES) ? cnt[i] : 0;
    sh[t] = v;
    for (int off = 1; off < SCAN_B; off <<= 1) {
        __syncthreads();
        int add = (t >= off) ? sh[t - off] : 0;
        __syncthreads();
        sh[t] += add;
    }
    if (i < N_NODES) row_ptr[i] = sh[t] - v;          // local exclusive
    if (t == SCAN_B - 1) blockSums[blockIdx.x] = sh[t];
}

__global__ void scan2_kernel(int* __restrict__ blockSums, int* __restrict__ row_ptr) {
    if (threadIdx.x == 0 && blockIdx.x == 0) {
        int run = 0;
        for (int b = 0; b < SCAN_NB; ++b) { int s = blockSums[b]; blockSums[b] = run; run += s; }
        row_ptr[N_NODES] = run;   // == N_EDGES
    }
}

__global__ void scan3_kernel(int* __restrict__ row_ptr, const int* __restrict__ blockSums,
                             int* __restrict__ cursor) {
    int i = blockIdx.x * blockDim.x + threadIdx.x;
    if (i < N_NODES) {
        int v = row_ptr[i] + blockSums[i / SCAN_B];
        row_ptr[i] = v;
        cursor[i] = v;
    }
}

// ---------------- CSR fill ----------------
__global__ void fill_csr_kernel(const int* __restrict__ src, const int* __restrict__ dst,
                                int* __restrict__ cursor, int* __restrict__ csr_src) {
    int e = blockIdx.x * blockDim.x + threadIdx.x;
    if (e < N_EDGES) {
        int d = dst[e];
        int p = atomicAdd(&cursor[d], 1);
        csr_src[p] = src[e];
    }
}

// ---------------- GEMM1: out[r][c] = dinv[r] * (x[N,256] @ W1[256,128]) ----------------
// LDS-tiled: 64 rows x 128 cols per block (256 thr), K-chunks of 32.
__global__ __launch_bounds__(256) void gemm1_kernel(const float* __restrict__ x,
                                                    const float* __restrict__ W,
                                                    const float* __restrict__ dinv,
                                                    float* __restrict__ out) {
    __shared__ float xs[32][64];     // k-major x tile (8 KB)
    __shared__ float ws[32][128];    // k-major W tile (16 KB)
    const int tid = threadIdx.x;
    const int row0 = blockIdx.x * 64;
    const int c0 = (tid & 31) * 4;          // 32 col-groups * 4
    const int r0 = (tid >> 5) * 8;          // 8 row-groups * 8

    float acc[8][4];
#pragma unroll
    for (int r = 0; r < 8; ++r)
#pragma unroll
        for (int c = 0; c < 4; ++c) acc[r][c] = 0.f;

    // staging assignments
    const int lr = tid >> 2;                // 0..63 tile row
    const int lk = (tid & 3) * 8;           // k offset within chunk
    int grow = row0 + lr;
    if (grow > N_NODES - 1) grow = N_NODES - 1;
    const float* xrow = x + (size_t)grow * 256;
    const int wk = tid >> 3;                // 0..31 k within chunk
    const int wc = (tid & 7) * 16;          // 8 groups * 16 cols

    for (int kc = 0; kc < 8; ++kc) {
        // issue global loads early
        float4 a0 = *(const float4*)&xrow[kc * 32 + lk];
        float4 a1 = *(const float4*)&xrow[kc * 32 + lk + 4];
        const float* wsrc = &W[(size_t)(kc * 32 + wk) * 128 + wc];
        float4 w0 = *(const float4*)&wsrc[0];
        float4 w1 = *(const float4*)&wsrc[4];
        float4 w2 = *(const float4*)&wsrc[8];
        float4 w3 = *(const float4*)&wsrc[12];

        if (kc > 0) __syncthreads();        // prev compute done
        xs[lk + 0][lr] = a0.x; xs[lk + 1][lr] = a0.y;
        xs[lk + 2][lr] = a0.z; xs[lk + 3][lr] = a0.w;
        xs[lk + 4][lr] = a1.x; xs[lk + 5][lr] = a1.y;
        xs[lk + 6][lr] = a1.z; xs[lk + 7][lr] = a1.w;
        *(float4*)&ws[wk][wc + 0]  = w0;
        *(float4*)&ws[wk][wc + 4]  = w1;
        *(float4*)&ws[wk][wc + 8]  = w2;
        *(float4*)&ws[wk][wc + 12] = w3;
        __syncthreads();

#pragma unroll 8
        for (int k = 0; k < 32; ++k) {
            float wv[4], xv[8];
            *(float4*)&wv[0] = *(const float4*)&ws[k][c0];
            *(float4*)&xv[0] = *(const float4*)&xs[k][r0];
            *(float4*)&xv[4] = *(const float4*)&xs[k][r0 + 4];
#pragma unroll
            for (int r = 0; r < 8; ++r)
#pragma unroll
                for (int c = 0; c < 4; ++c) acc[r][c] += xv[r] * wv[c];
        }
    }

#pragma unroll
    for (int r = 0; r < 8; ++r) {
        int row = row0 + r0 + r;
        if (row < N_NODES) {
            float dv = dinv[row];
            float4 v = make_float4(acc[r][0] * dv, acc[r][1] * dv,
                                   acc[r][2] * dv, acc[r][3] * dv);
            *(float4*)&out[(size_t)row * 128 + c0] = v;
        }
    }
}

// ---------------- GEMM2: out[r][c] = dinv[r] * (h[N,128] @ W2[128,64]) ----------------
// 128 rows x 64 cols per block (256 thr), K-chunks of 32.
__global__ __launch_bounds__(256) void gemm2_kernel(const float* __restrict__ h,
                                                    const float* __restrict__ W,
                                                    const float* __restrict__ dinv,
                                                    float* __restrict__ out) {
    __shared__ float xs[32][128];    // 16 KB
    __shared__ float ws[32][64];     // 8 KB
    const int tid = threadIdx.x;
    const int row0 = blockIdx.x * 128;
    const int c0 = (tid & 15) * 4;          // 16 col-groups * 4
    const int r0 = (tid >> 4) * 8;          // 16 row-groups * 8

    float acc[8][4];
#pragma unroll
    for (int r = 0; r < 8; ++r)
#pragma unroll
        for (int c = 0; c < 4; ++c) acc[r][c] = 0.f;

    const int lr = tid >> 1;                // 0..127 tile row
    const int lk = (tid & 1) * 16;          // k offset within chunk
    int grow = row0 + lr;
    if (grow > N_NODES - 1) grow = N_NODES - 1;
    const float* hrow = h + (size_t)grow * 128;
    const int wk = tid >> 3;                // 0..31
    const int wc = (tid & 7) * 8;           // 8 groups * 8 cols

    for (int kc = 0; kc < 4; ++kc) {
        float4 a0 = *(const float4*)&hrow[kc * 32 + lk];
        float4 a1 = *(const float4*)&hrow[kc * 32 + lk + 4];
        float4 a2 = *(const float4*)&hrow[kc * 32 + lk + 8];
        float4 a3 = *(const float4*)&hrow[kc * 32 + lk + 12];
        const float* wsrc = &W[(size_t)(kc * 32 + wk) * 64 + wc];
        float4 w0 = *(const float4*)&wsrc[0];
        float4 w1 = *(const float4*)&wsrc[4];

        if (kc > 0) __syncthreads();
        xs[lk + 0][lr]  = a0.x; xs[lk + 1][lr]  = a0.y;
        xs[lk + 2][lr]  = a0.z; xs[lk + 3][lr]  = a0.w;
        xs[lk + 4][lr]  = a1.x; xs[lk + 5][lr]  = a1.y;
        xs[lk + 6][lr]  = a1.z; xs[lk + 7][lr]  = a1.w;
        xs[lk + 8][lr]  = a2.x; xs[lk + 9][lr]  = a2.y;
        xs[lk + 10][lr] = a2.z; xs[lk + 11][lr] = a2.w;
        xs[lk + 12][lr] = a3.x; xs[lk + 13][lr] = a3.y;
        xs[lk + 14][lr] = a3.z; xs[lk + 15][lr] = a3.w;
        *(float4*)&ws[wk][wc + 0] = w0;
        *(float4*)&ws[wk][wc + 4] = w1;
        __syncthreads();

#pragma unroll 8
        for (int k = 0; k < 32; ++k) {
            float wv[4], xv[8];
            *(float4*)&wv[0] = *(const float4*)&ws[k][c0];
            *(float4*)&xv[0] = *(const float4*)&xs[k][r0];
            *(float4*)&xv[4] = *(const float4*)&xs[k][r0 + 4];
#pragma unroll
            for (int r = 0; r < 8; ++r)
#pragma unroll
                for (int c = 0; c < 4; ++c) acc[r][c] += xv[r] * wv[c];
        }
    }

#pragma unroll
    for (int r = 0; r < 8; ++r) {
        int row = row0 + r0 + r;
        if (row < N_NODES) {
            float dv = dinv[row];
            float4 v = make_float4(acc[r][0] * dv, acc[r][1] * dv,
                                   acc[r][2] * dv, acc[r][3] * dv);
            *(float4*)&out[(size_t)row * 64 + c0] = v;
        }
    }
}

// ---------------- agg1: h = relu(dinv .* (sum of pre-scaled xw' rows) + b1); F=128 ----------------
// xw' rows already scaled by dinv (GEMM epilogue). One wave/node, float2 per lane.
__global__ __launch_bounds__(256) void agg1_kernel(const float* __restrict__ xw,
                                                   const int* __restrict__ csr_src,
                                                   const int* __restrict__ row_ptr,
                                                   const float* __restrict__ dinv,
                                                   const float* __restrict__ bias,
                                                   float* __restrict__ h) {
    const int node = blockIdx.x * 4 + (threadIdx.x >> 6);
    const int lane = threadIdx.x & 63;
    const float2* xw2 = (const float2*)xw;
    const float2* b2 = (const float2*)bias;
    float2 acc = xw2[(size_t)node * 64 + lane];        // self (xw' already has dinv)
    const int beg = row_ptr[node], end = row_ptr[node + 1];
    for (int e = beg; e < end; ++e) {
        int s = csr_src[e];
        float2 v = xw2[(size_t)s * 64 + lane];
        acc.x += v.x; acc.y += v.y;
    }
    const float di = dinv[node];
    float2 bv = b2[lane];
    float v0 = acc.x * di + bv.x;
    float v1 = acc.y * di + bv.y;
    float2 o = make_float2(v0 > 0.f ? v0 : 0.f, v1 > 0.f ? v1 : 0.f);
    *(float2*)&h[(size_t)node * 128 + lane * 2] = o;
}

// ---------------- agg2 + mean-pool: F=64 ----------------
__global__ __launch_bounds__(256) void agg2_pool_kernel(const float* __restrict__ xw,
                                                        const int* __restrict__ csr_src,
                                                        const int* __restrict__ row_ptr,
                                                        const float* __restrict__ dinv,
                                                        const float* __restrict__ bias,
                                                        const int* __restrict__ batch,
                                                        float* __restrict__ gsum,
                                                        float* __restrict__ gcnt) {
    const int node = blockIdx.x * 4 + (threadIdx.x >> 6);
    const int lane = threadIdx.x & 63;
    float acc = xw[(size_t)node * 64 + lane];          // self (pre-scaled)
    const int beg = row_ptr[node], end = row_ptr[node + 1];
    for (int e = beg; e < end; ++e) {
        int s = csr_src[e];
        acc += xw[(size_t)s * 64 + lane];
    }
    float val = acc * dinv[node] + bias[lane];
    int b = batch[node];
    atomicAdd(&gsum[b * 64 + lane], val);
    if (lane == 0) atomicAdd(&gcnt[b], 1.0f);
}

// ---------------- head: mean -> fc -> log_softmax ----------------
__global__ void head_kernel(const float* __restrict__ gsum, const float* __restrict__ gcnt,
                            const float* __restrict__ fcW, const float* __restrict__ fcb,
                            float* __restrict__ out) {
    int g = blockIdx.x * blockDim.x + threadIdx.x;
    if (g >= NUM_GRAPHS) return;
    float c = gcnt[g];
    c = c > 1.f ? c : 1.f;
    float inv = 1.f / c;
    float logits[4];
#pragma unroll
    for (int j = 0; j < 4; ++j) logits[j] = fcb[j];
    for (int k = 0; k < 64; ++k) {
        float m = gsum[g * 64 + k] * inv;
#pragma unroll
        for (int j = 0; j < 4; ++j) logits[j] += m * fcW[k * 4 + j];
    }
    float mx = logits[0];
#pragma unroll
    for (int j = 1; j < 4; ++j) mx = logits[j] > mx ? logits[j] : mx;
    float s = 0.f;
#pragma unroll
    for (int j = 0; j < 4; ++j) s += expf(logits[j] - mx);
    float lse = mx + logf(s);
#pragma unroll
    for (int j = 0; j < 4; ++j) out[g * 4 + j] = logits[j] - lse;
}

extern "C" void kernel_launch(void* const* d_in, const int* in_sizes, int n_in,
                              void* d_out, int out_size, void* d_ws, size_t ws_size,
                              hipStream_t stream) {
    const float* x     = (const float*)d_in[0];
    const int*   ei    = (const int*)d_in[1];     // [2, E]
    const int*   batch = (const int*)d_in[2];
    const float* W1    = (const float*)d_in[3];
    const float* b1    = (const float*)d_in[4];
    const float* W2    = (const float*)d_in[5];
    const float* b2    = (const float*)d_in[6];
    const float* fcW   = (const float*)d_in[7];
    const float* fcb   = (const float*)d_in[8];
    float* out = (float*)d_out;

    const int* src = ei;
    const int* dst = ei + N_EDGES;

    // workspace carve-up (256B aligned)
    size_t o = 0;
    char* wsb = (char*)d_ws;
    auto take = [&](size_t bytes) -> void* {
        void* p = wsb + o;
        o += (bytes + 255) & ~(size_t)255;
        return p;
    };
    int*   cnt       = (int*)take((size_t)N_NODES * 4);
    float* dinv      = (float*)take((size_t)N_NODES * 4);
    int*   row_ptr   = (int*)take((size_t)(N_NODES + 1) * 4);
    int*   cursor    = (int*)take((size_t)N_NODES * 4);
    int*   csr_src   = (int*)take((size_t)N_EDGES * 4);
    int*   blockSums = (int*)take(1024);
    float* bufA      = (float*)take((size_t)N_NODES * 128 * 4);  // xw1', later xw2'
    float* bufB      = (float*)take((size_t)N_NODES * 128 * 4);  // h1
    float* gsum      = (float*)take((size_t)NUM_GRAPHS * 64 * 4);
    float* gcnt      = (float*)take((size_t)NUM_GRAPHS * 4);
    (void)ws_size;

    const int TB = 256;

    // zero accumulators (ws is poisoned 0xAA before every call)
    zero_i32_kernel<<<(N_NODES + TB - 1) / TB, TB, 0, stream>>>(cnt, N_NODES);
    zero_i32_kernel<<<(NUM_GRAPHS * 64 + TB - 1) / TB, TB, 0, stream>>>((int*)gsum, NUM_GRAPHS * 64);
    zero_i32_kernel<<<(NUM_GRAPHS + TB - 1) / TB, TB, 0, stream>>>((int*)gcnt, NUM_GRAPHS);

    // degrees + dinv (needed by gemm1 epilogue)
    count_dst_kernel<<<(N_EDGES + TB - 1) / TB, TB, 0, stream>>>(dst, cnt);
    dinv_kernel<<<(N_NODES + TB - 1) / TB, TB, 0, stream>>>(cnt, dinv);

    // row_ptr = exclusive scan(cnt); cursor = row_ptr
    scan1_kernel<<<SCAN_NB, SCAN_B, 0, stream>>>(cnt, row_ptr, blockSums);
    scan2_kernel<<<1, 1, 0, stream>>>(blockSums, row_ptr);
    scan3_kernel<<<(N_NODES + TB - 1) / TB, TB, 0, stream>>>(row_ptr, blockSums, cursor);

    // CSR fill (dst-grouped src lists)
    fill_csr_kernel<<<(N_EDGES + TB - 1) / TB, TB, 0, stream>>>(src, dst, cursor, csr_src);

    // layer 1: xw1' = dinv .* (x @ W1); h1 = relu(dinv .* agg(xw1') + b1)
    gemm1_kernel<<<(N_NODES + 63) / 64, TB, 0, stream>>>(x, W1, dinv, bufA);
    agg1_kernel<<<N_NODES / 4, TB, 0, stream>>>(bufA, csr_src, row_ptr, dinv, b1, bufB);

    // layer 2 + pooling
    gemm2_kernel<<<(N_NODES + 127) / 128, TB, 0, stream>>>(bufB, W2, dinv, bufA);
    agg2_pool_kernel<<<N_NODES / 4, TB, 0, stream>>>(bufA, csr_src, row_ptr, dinv, b2, batch,
                                                     gsum, gcnt);

    // head
    head_kernel<<<(NUM_GRAPHS + TB - 1) / TB, TB, 0, stream>>>(gsum, gcnt, fcW, fcb, out);
}

// Round 3
// 672.780 us; speedup vs baseline: 1.9298x; 1.2685x over previous
//
#include <hip/hip_runtime.h>
#include <hip/hip_bf16.h>

#define N_NODES 100000
#define N_EDGES 1600000
#define NUM_GRAPHS 1000
#define SCAN_B 1024
#define SCAN_NB ((N_NODES + SCAN_B - 1) / SCAN_B)   // 98

// ---------------- utility ----------------
__global__ void zero_i32_kernel(int* __restrict__ p, int n) {
    int i = blockIdx.x * blockDim.x + threadIdx.x;
    if (i < n) p[i] = 0;
}

// ---------------- degree / dinv ----------------
__global__ void count_dst_kernel(const int* __restrict__ dst, int* __restrict__ cnt) {
    int e = blockIdx.x * blockDim.x + threadIdx.x;
    if (e < N_EDGES) atomicAdd(&cnt[dst[e]], 1);
}

__global__ void dinv_kernel(const int* __restrict__ cnt, float* __restrict__ dinv) {
    int i = blockIdx.x * blockDim.x + threadIdx.x;
    if (i < N_NODES) dinv[i] = rsqrtf((float)(cnt[i] + 1));  // +1 self loop
}

// ---------------- exclusive scan (row_ptr) ----------------
__global__ void scan1_kernel(const int* __restrict__ cnt, int* __restrict__ row_ptr,
                             int* __restrict__ blockSums) {
    __shared__ int sh[SCAN_B];
    int t = threadIdx.x;
    int i = blockIdx.x * SCAN_B + t;
    int v = (i < N_NODES) ? cnt[i] : 0;
    sh[t] = v;
    for (int off = 1; off < SCAN_B; off <<= 1) {
        __syncthreads();
        int add = (t >= off) ? sh[t - off] : 0;
        __syncthreads();
        sh[t] += add;
    }
    if (i < N_NODES) row_ptr[i] = sh[t] - v;          // local exclusive
    if (t == SCAN_B - 1) blockSums[blockIdx.x] = sh[t];
}

__global__ void scan2_kernel(int* __restrict__ blockSums, int* __restrict__ row_ptr) {
    if (threadIdx.x == 0 && blockIdx.x == 0) {
        int run = 0;
        for (int b = 0; b < SCAN_NB; ++b) { int s = blockSums[b]; blockSums[b] = run; run += s; }
        row_ptr[N_NODES] = run;   // == N_EDGES
    }
}

__global__ void scan3_kernel(int* __restrict__ row_ptr, const int* __restrict__ blockSums,
                             int* __restrict__ cursor) {
    int i = blockIdx.x * blockDim.x + threadIdx.x;
    if (i < N_NODES) {
        int v = row_ptr[i] + blockSums[i / SCAN_B];
        row_ptr[i] = v;
        cursor[i] = v;
    }
}

// ---------------- CSR fill ----------------
__global__ void fill_csr_kernel(const int* __restrict__ src, const int* __restrict__ dst,
                                int* __restrict__ cursor, int* __restrict__ csr_src) {
    int e = blockIdx.x * blockDim.x + threadIdx.x;
    if (e < N_EDGES) {
        int d = dst[e];
        int p = atomicAdd(&cursor[d], 1);
        csr_src[p] = src[e];
    }
}

// ---------------- GEMM1: out[r][c] = dinv[r] * (x[N,256] @ W1[256,128]) ----------------
__global__ __launch_bounds__(256) void gemm1_kernel(const float* __restrict__ x,
                                                    const float* __restrict__ W,
                                                    const float* __restrict__ dinv,
                                                    float* __restrict__ out) {
    __shared__ float xs[32][64];     // k-major x tile (8 KB)
    __shared__ float ws[32][128];    // k-major W tile (16 KB)
    const int tid = threadIdx.x;
    const int row0 = blockIdx.x * 64;
    const int c0 = (tid & 31) * 4;
    const int r0 = (tid >> 5) * 8;

    float acc[8][4];
#pragma unroll
    for (int r = 0; r < 8; ++r)
#pragma unroll
        for (int c = 0; c < 4; ++c) acc[r][c] = 0.f;

    const int lr = tid >> 2;
    const int lk = (tid & 3) * 8;
    int grow = row0 + lr;
    if (grow > N_NODES - 1) grow = N_NODES - 1;
    const float* xrow = x + (size_t)grow * 256;
    const int wk = tid >> 3;
    const int wc = (tid & 7) * 16;

    for (int kc = 0; kc < 8; ++kc) {
        float4 a0 = *(const float4*)&xrow[kc * 32 + lk];
        float4 a1 = *(const float4*)&xrow[kc * 32 + lk + 4];
        const float* wsrc = &W[(size_t)(kc * 32 + wk) * 128 + wc];
        float4 w0 = *(const float4*)&wsrc[0];
        float4 w1 = *(const float4*)&wsrc[4];
        float4 w2 = *(const float4*)&wsrc[8];
        float4 w3 = *(const float4*)&wsrc[12];

        if (kc > 0) __syncthreads();
        xs[lk + 0][lr] = a0.x; xs[lk + 1][lr] = a0.y;
        xs[lk + 2][lr] = a0.z; xs[lk + 3][lr] = a0.w;
        xs[lk + 4][lr] = a1.x; xs[lk + 5][lr] = a1.y;
        xs[lk + 6][lr] = a1.z; xs[lk + 7][lr] = a1.w;
        *(float4*)&ws[wk][wc + 0]  = w0;
        *(float4*)&ws[wk][wc + 4]  = w1;
        *(float4*)&ws[wk][wc + 8]  = w2;
        *(float4*)&ws[wk][wc + 12] = w3;
        __syncthreads();

#pragma unroll 8
        for (int k = 0; k < 32; ++k) {
            float wv[4], xv[8];
            *(float4*)&wv[0] = *(const float4*)&ws[k][c0];
            *(float4*)&xv[0] = *(const float4*)&xs[k][r0];
            *(float4*)&xv[4] = *(const float4*)&xs[k][r0 + 4];
#pragma unroll
            for (int r = 0; r < 8; ++r)
#pragma unroll
                for (int c = 0; c < 4; ++c) acc[r][c] += xv[r] * wv[c];
        }
    }

#pragma unroll
    for (int r = 0; r < 8; ++r) {
        int row = row0 + r0 + r;
        if (row < N_NODES) {
            float dv = dinv[row];
            float4 v = make_float4(acc[r][0] * dv, acc[r][1] * dv,
                                   acc[r][2] * dv, acc[r][3] * dv);
            *(float4*)&out[(size_t)row * 128 + c0] = v;
        }
    }
}

// ---------------- GEMM2: out[r][c] = dinv[r] * (h[N,128] @ W2[128,64]) ----------------
__global__ __launch_bounds__(256) void gemm2_kernel(const float* __restrict__ h,
                                                    const float* __restrict__ W,
                                                    const float* __restrict__ dinv,
                                                    float* __restrict__ out) {
    __shared__ float xs[32][128];    // 16 KB
    __shared__ float ws[32][64];     // 8 KB
    const int tid = threadIdx.x;
    const int row0 = blockIdx.x * 128;
    const int c0 = (tid & 15) * 4;
    const int r0 = (tid >> 4) * 8;

    float acc[8][4];
#pragma unroll
    for (int r = 0; r < 8; ++r)
#pragma unroll
        for (int c = 0; c < 4; ++c) acc[r][c] = 0.f;

    const int lr = tid >> 1;
    const int lk = (tid & 1) * 16;
    int grow = row0 + lr;
    if (grow > N_NODES - 1) grow = N_NODES - 1;
    const float* hrow = h + (size_t)grow * 128;
    const int wk = tid >> 3;
    const int wc = (tid & 7) * 8;

    for (int kc = 0; kc < 4; ++kc) {
        float4 a0 = *(const float4*)&hrow[kc * 32 + lk];
        float4 a1 = *(const float4*)&hrow[kc * 32 + lk + 4];
        float4 a2 = *(const float4*)&hrow[kc * 32 + lk + 8];
        float4 a3 = *(const float4*)&hrow[kc * 32 + lk + 12];
        const float* wsrc = &W[(size_t)(kc * 32 + wk) * 64 + wc];
        float4 w0 = *(const float4*)&wsrc[0];
        float4 w1 = *(const float4*)&wsrc[4];

        if (kc > 0) __syncthreads();
        xs[lk + 0][lr]  = a0.x; xs[lk + 1][lr]  = a0.y;
        xs[lk + 2][lr]  = a0.z; xs[lk + 3][lr]  = a0.w;
        xs[lk + 4][lr]  = a1.x; xs[lk + 5][lr]  = a1.y;
        xs[lk + 6][lr]  = a1.z; xs[lk + 7][lr]  = a1.w;
        xs[lk + 8][lr]  = a2.x; xs[lk + 9][lr]  = a2.y;
        xs[lk + 10][lr] = a2.z; xs[lk + 11][lr] = a2.w;
        xs[lk + 12][lr] = a3.x; xs[lk + 13][lr] = a3.y;
        xs[lk + 14][lr] = a3.z; xs[lk + 15][lr] = a3.w;
        *(float4*)&ws[wk][wc + 0] = w0;
        *(float4*)&ws[wk][wc + 4] = w1;
        __syncthreads();

#pragma unroll 8
        for (int k = 0; k < 32; ++k) {
            float wv[4], xv[8];
            *(float4*)&wv[0] = *(const float4*)&ws[k][c0];
            *(float4*)&xv[0] = *(const float4*)&xs[k][r0];
            *(float4*)&xv[4] = *(const float4*)&xs[k][r0 + 4];
#pragma unroll
            for (int r = 0; r < 8; ++r)
#pragma unroll
                for (int c = 0; c < 4; ++c) acc[r][c] += xv[r] * wv[c];
        }
    }

#pragma unroll
    for (int r = 0; r < 8; ++r) {
        int row = row0 + r0 + r;
        if (row < N_NODES) {
            float dv = dinv[row];
            float4 v = make_float4(acc[r][0] * dv, acc[r][1] * dv,
                                   acc[r][2] * dv, acc[r][3] * dv);
            *(float4*)&out[(size_t)row * 64 + c0] = v;
        }
    }
}

// ---------------- agg1: h = relu(dinv .* (sum of pre-scaled xw' rows) + b1); F=128 ----------------
// 8-wide unrolled predicated gather batches: 8 row-loads in flight per wave.
__global__ __launch_bounds__(256) void agg1_kernel(const float* __restrict__ xw,
                                                   const int* __restrict__ csr_src,
                                                   const int* __restrict__ row_ptr,
                                                   const float* __restrict__ dinv,
                                                   const float* __restrict__ bias,
                                                   float* __restrict__ h) {
    const int node = blockIdx.x * 4 + (threadIdx.x >> 6);
    const int lane = threadIdx.x & 63;
    const float2* xw2 = (const float2*)xw;
    const float2* b2p = (const float2*)bias;
    float2 acc = xw2[(size_t)node * 64 + lane];        // self (xw' already has dinv)
    const int beg = row_ptr[node], end = row_ptr[node + 1];
    for (int e = beg; e < end; e += 8) {
        int s[8];
        s[0] = csr_src[e];
#pragma unroll
        for (int i = 1; i < 8; ++i)
            s[i] = (e + i < end) ? csr_src[e + i] : s[0];
        float2 v[8];
#pragma unroll
        for (int i = 0; i < 8; ++i)
            v[i] = xw2[(size_t)s[i] * 64 + lane];
        acc.x += v[0].x; acc.y += v[0].y;
#pragma unroll
        for (int i = 1; i < 8; ++i) {
            if (e + i < end) { acc.x += v[i].x; acc.y += v[i].y; }
        }
    }
    const float di = dinv[node];
    float2 bv = b2p[lane];
    float v0 = acc.x * di + bv.x;
    float v1 = acc.y * di + bv.y;
    float2 o = make_float2(v0 > 0.f ? v0 : 0.f, v1 > 0.f ? v1 : 0.f);
    *(float2*)&h[(size_t)node * 128 + lane * 2] = o;
}

// ---------------- agg2 + mean-pool: F=64, LDS-combined atomics ----------------
__global__ __launch_bounds__(256) void agg2_pool_kernel(const float* __restrict__ xw,
                                                        const int* __restrict__ csr_src,
                                                        const int* __restrict__ row_ptr,
                                                        const float* __restrict__ dinv,
                                                        const float* __restrict__ bias,
                                                        const int* __restrict__ batch,
                                                        float* __restrict__ gsum,
                                                        float* __restrict__ gcnt) {
    __shared__ float part[4][64];
    __shared__ int bsh[4];
    const int w = threadIdx.x >> 6;
    const int node = blockIdx.x * 4 + w;
    const int lane = threadIdx.x & 63;
    float acc = xw[(size_t)node * 64 + lane];          // self (pre-scaled)
    const int beg = row_ptr[node], end = row_ptr[node + 1];
    for (int e = beg; e < end; e += 8) {
        int s[8];
        s[0] = csr_src[e];
#pragma unroll
        for (int i = 1; i < 8; ++i)
            s[i] = (e + i < end) ? csr_src[e + i] : s[0];
        float v[8];
#pragma unroll
        for (int i = 0; i < 8; ++i)
            v[i] = xw[(size_t)s[i] * 64 + lane];
        acc += v[0];
#pragma unroll
        for (int i = 1; i < 8; ++i) {
            if (e + i < end) acc += v[i];
        }
    }
    float val = acc * dinv[node] + bias[lane];
    part[w][lane] = val;
    if (lane == 0) bsh[w] = batch[node];
    __syncthreads();
    if (w == 0) {
        int b0 = bsh[0], b1 = bsh[1], b2 = bsh[2], b3 = bsh[3];
        if (b0 == b1 && b1 == b2 && b2 == b3) {
            float s = part[0][lane] + part[1][lane] + part[2][lane] + part[3][lane];
            atomicAdd(&gsum[b0 * 64 + lane], s);
            if (lane == 0) atomicAdd(&gcnt[b0], 4.0f);
        } else {
            atomicAdd(&gsum[b0 * 64 + lane], part[0][lane]);
            atomicAdd(&gsum[b1 * 64 + lane], part[1][lane]);
            atomicAdd(&gsum[b2 * 64 + lane], part[2][lane]);
            atomicAdd(&gsum[b3 * 64 + lane], part[3][lane]);
            if (lane == 0) {
                atomicAdd(&gcnt[b0], 1.0f);
                atomicAdd(&gcnt[b1], 1.0f);
                atomicAdd(&gcnt[b2], 1.0f);
                atomicAdd(&gcnt[b3], 1.0f);
            }
        }
    }
}

// ---------------- head: mean -> fc -> log_softmax ----------------
__global__ void head_kernel(const float* __restrict__ gsum, const float* __restrict__ gcnt,
                            const float* __restrict__ fcW, const float* __restrict__ fcb,
                            float* __restrict__ out) {
    int g = blockIdx.x * blockDim.x + threadIdx.x;
    if (g >= NUM_GRAPHS) return;
    float c = gcnt[g];
    c = c > 1.f ? c : 1.f;
    float inv = 1.f / c;
    float logits[4];
#pragma unroll
    for (int j = 0; j < 4; ++j) logits[j] = fcb[j];
    for (int k = 0; k < 64; ++k) {
        float m = gsum[g * 64 + k] * inv;
#pragma unroll
        for (int j = 0; j < 4; ++j) logits[j] += m * fcW[k * 4 + j];
    }
    float mx = logits[0];
#pragma unroll
    for (int j = 1; j < 4; ++j) mx = logits[j] > mx ? logits[j] : mx;
    float s = 0.f;
#pragma unroll
    for (int j = 0; j < 4; ++j) s += expf(logits[j] - mx);
    float lse = mx + logf(s);
#pragma unroll
    for (int j = 0; j < 4; ++j) out[g * 4 + j] = logits[j] - lse;
}

extern "C" void kernel_launch(void* const* d_in, const int* in_sizes, int n_in,
                              void* d_out, int out_size, void* d_ws, size_t ws_size,
                              hipStream_t stream) {
    const float* x     = (const float*)d_in[0];
    const int*   ei    = (const int*)d_in[1];     // [2, E]
    const int*   batch = (const int*)d_in[2];
    const float* W1    = (const float*)d_in[3];
    const float* b1    = (const float*)d_in[4];
    const float* W2    = (const float*)d_in[5];
    const float* b2    = (const float*)d_in[6];
    const float* fcW   = (const float*)d_in[7];
    const float* fcb   = (const float*)d_in[8];
    float* out = (float*)d_out;

    const int* src = ei;
    const int* dst = ei + N_EDGES;

    size_t o = 0;
    char* wsb = (char*)d_ws;
    auto take = [&](size_t bytes) -> void* {
        void* p = wsb + o;
        o += (bytes + 255) & ~(size_t)255;
        return p;
    };
    int*   cnt       = (int*)take((size_t)N_NODES * 4);
    float* dinv      = (float*)take((size_t)N_NODES * 4);
    int*   row_ptr   = (int*)take((size_t)(N_NODES + 1) * 4);
    int*   cursor    = (int*)take((size_t)N_NODES * 4);
    int*   csr_src   = (int*)take((size_t)N_EDGES * 4);
    int*   blockSums = (int*)take(1024);
    float* bufA      = (float*)take((size_t)N_NODES * 128 * 4);  // xw1', later xw2'
    float* bufB      = (float*)take((size_t)N_NODES * 128 * 4);  // h1
    float* gsum      = (float*)take((size_t)NUM_GRAPHS * 64 * 4);
    float* gcnt      = (float*)take((size_t)NUM_GRAPHS * 4);
    (void)ws_size;

    const int TB = 256;

    zero_i32_kernel<<<(N_NODES + TB - 1) / TB, TB, 0, stream>>>(cnt, N_NODES);
    zero_i32_kernel<<<(NUM_GRAPHS * 64 + TB - 1) / TB, TB, 0, stream>>>((int*)gsum, NUM_GRAPHS * 64);
    zero_i32_kernel<<<(NUM_GRAPHS + TB - 1) / TB, TB, 0, stream>>>((int*)gcnt, NUM_GRAPHS);

    count_dst_kernel<<<(N_EDGES + TB - 1) / TB, TB, 0, stream>>>(dst, cnt);
    dinv_kernel<<<(N_NODES + TB - 1) / TB, TB, 0, stream>>>(cnt, dinv);

    scan1_kernel<<<SCAN_NB, SCAN_B, 0, stream>>>(cnt, row_ptr, blockSums);
    scan2_kernel<<<1, 1, 0, stream>>>(blockSums, row_ptr);
    scan3_kernel<<<(N_NODES + TB - 1) / TB, TB, 0, stream>>>(row_ptr, blockSums, cursor);

    fill_csr_kernel<<<(N_EDGES + TB - 1) / TB, TB, 0, stream>>>(src, dst, cursor, csr_src);

    gemm1_kernel<<<(N_NODES + 63) / 64, TB, 0, stream>>>(x, W1, dinv, bufA);
    agg1_kernel<<<N_NODES / 4, TB, 0, stream>>>(bufA, csr_src, row_ptr, dinv, b1, bufB);

    gemm2_kernel<<<(N_NODES + 127) / 128, TB, 0, stream>>>(bufB, W2, dinv, bufA);
    agg2_pool_kernel<<<N_NODES / 4, TB, 0, stream>>>(bufA, csr_src, row_ptr, dinv, b2, batch,
                                                     gsum, gcnt);

    head_kernel<<<(NUM_GRAPHS + TB - 1) / TB, TB, 0, stream>>>(gsum, gcnt, fcW, fcb, out);
}

// Round 4
// 529.459 us; speedup vs baseline: 2.4522x; 1.2707x over previous
//
#include <hip/hip_runtime.h>
#include <hip/hip_bf16.h>

#define N_NODES 100000
#define N_EDGES 1600000
#define NUM_GRAPHS 1000
#define SCAN_B 1024
#define SCAN_NB ((N_NODES + SCAN_B - 1) / SCAN_B)   // 98

// gemm1 tile blocks: 100000/64 = 1563; fill blocks: 781 (2049 edges each)
#define G1_BLOCKS 1563
#define FILL_BLOCKS 781
#define FILL_CHUNK 2049
#define FUSED_BLOCKS 2345   // b%3==2 -> fill (781), else gemm (1564, last unused)

__device__ __forceinline__ unsigned short f2bf(float f) {
    unsigned int u = __float_as_uint(f);
    u = u + 0x7fffu + ((u >> 16) & 1u);      // round-to-nearest-even
    return (unsigned short)(u >> 16);
}

// ---------------- utility ----------------
__global__ void zero_i32_kernel(int* __restrict__ p, int n) {
    int i = blockIdx.x * blockDim.x + threadIdx.x;
    if (i < n) p[i] = 0;
}

// ---------------- degree / dinv ----------------
__global__ void count_dst_kernel(const int* __restrict__ dst, int* __restrict__ cnt) {
    int e = blockIdx.x * blockDim.x + threadIdx.x;
    if (e < N_EDGES) atomicAdd(&cnt[dst[e]], 1);
}

__global__ void dinv_kernel(const int* __restrict__ cnt, float* __restrict__ dinv) {
    int i = blockIdx.x * blockDim.x + threadIdx.x;
    if (i < N_NODES) dinv[i] = rsqrtf((float)(cnt[i] + 1));  // +1 self loop
}

// ---------------- exclusive scan (row_ptr) ----------------
__global__ void scan1_kernel(const int* __restrict__ cnt, int* __restrict__ row_ptr,
                             int* __restrict__ blockSums) {
    __shared__ int sh[SCAN_B];
    int t = threadIdx.x;
    int i = blockIdx.x * SCAN_B + t;
    int v = (i < N_NODES) ? cnt[i] : 0;
    sh[t] = v;
    for (int off = 1; off < SCAN_B; off <<= 1) {
        __syncthreads();
        int add = (t >= off) ? sh[t - off] : 0;
        __syncthreads();
        sh[t] += add;
    }
    if (i < N_NODES) row_ptr[i] = sh[t] - v;
    if (t == SCAN_B - 1) blockSums[blockIdx.x] = sh[t];
}

__global__ void scan2_kernel(int* __restrict__ blockSums, int* __restrict__ row_ptr) {
    if (threadIdx.x == 0 && blockIdx.x == 0) {
        int run = 0;
        for (int b = 0; b < SCAN_NB; ++b) { int s = blockSums[b]; blockSums[b] = run; run += s; }
        row_ptr[N_NODES] = run;
    }
}

__global__ void scan3_kernel(int* __restrict__ row_ptr, const int* __restrict__ blockSums,
                             int* __restrict__ cursor) {
    int i = blockIdx.x * blockDim.x + threadIdx.x;
    if (i < N_NODES) {
        int v = row_ptr[i] + blockSums[i / SCAN_B];
        row_ptr[i] = v;
        cursor[i] = v;
    }
}

// ---------------- fused: GEMM1 (bf16 out) + CSR fill ----------------
// role: blockIdx%3==2 -> fill chunk; else gemm tile.
// gemm: out_bf[r][c] = bf16(dinv[r] * (x[N,256] @ W1[256,128]))
__global__ __launch_bounds__(256) void gemm1_fill_kernel(const float* __restrict__ x,
                                                         const float* __restrict__ W,
                                                         const float* __restrict__ dinv,
                                                         unsigned short* __restrict__ outb,
                                                         const int* __restrict__ esrc,
                                                         const int* __restrict__ edst,
                                                         int* __restrict__ cursor,
                                                         int* __restrict__ csr_src) {
    __shared__ float xs[32][64];
    __shared__ float ws[32][128];
    const int b = blockIdx.x;
    const int tid = threadIdx.x;

    if (b % 3 == 2) {
        // ---- CSR fill role ----
        const int fid = b / 3;
        const int beg = fid * FILL_CHUNK;
        int end = beg + FILL_CHUNK;
        if (end > N_EDGES) end = N_EDGES;
        for (int e = beg + tid; e < end; e += 256) {
            int d = edst[e];
            int p = atomicAdd(&cursor[d], 1);
            csr_src[p] = esrc[e];
        }
        return;
    }

    // ---- GEMM role ----
    const int gid = b - b / 3;
    if (gid >= G1_BLOCKS) return;
    const int row0 = gid * 64;
    const int c0 = (tid & 31) * 4;
    const int r0 = (tid >> 5) * 8;

    float acc[8][4];
#pragma unroll
    for (int r = 0; r < 8; ++r)
#pragma unroll
        for (int c = 0; c < 4; ++c) acc[r][c] = 0.f;

    const int lr = tid >> 2;
    const int lk = (tid & 3) * 8;
    int grow = row0 + lr;
    if (grow > N_NODES - 1) grow = N_NODES - 1;
    const float* xrow = x + (size_t)grow * 256;
    const int wk = tid >> 3;
    const int wc = (tid & 7) * 16;

    for (int kc = 0; kc < 8; ++kc) {
        float4 a0 = *(const float4*)&xrow[kc * 32 + lk];
        float4 a1 = *(const float4*)&xrow[kc * 32 + lk + 4];
        const float* wsrc = &W[(size_t)(kc * 32 + wk) * 128 + wc];
        float4 w0 = *(const float4*)&wsrc[0];
        float4 w1 = *(const float4*)&wsrc[4];
        float4 w2 = *(const float4*)&wsrc[8];
        float4 w3 = *(const float4*)&wsrc[12];

        if (kc > 0) __syncthreads();
        xs[lk + 0][lr] = a0.x; xs[lk + 1][lr] = a0.y;
        xs[lk + 2][lr] = a0.z; xs[lk + 3][lr] = a0.w;
        xs[lk + 4][lr] = a1.x; xs[lk + 5][lr] = a1.y;
        xs[lk + 6][lr] = a1.z; xs[lk + 7][lr] = a1.w;
        *(float4*)&ws[wk][wc + 0]  = w0;
        *(float4*)&ws[wk][wc + 4]  = w1;
        *(float4*)&ws[wk][wc + 8]  = w2;
        *(float4*)&ws[wk][wc + 12] = w3;
        __syncthreads();

#pragma unroll 8
        for (int k = 0; k < 32; ++k) {
            float wv[4], xv[8];
            *(float4*)&wv[0] = *(const float4*)&ws[k][c0];
            *(float4*)&xv[0] = *(const float4*)&xs[k][r0];
            *(float4*)&xv[4] = *(const float4*)&xs[k][r0 + 4];
#pragma unroll
            for (int r = 0; r < 8; ++r)
#pragma unroll
                for (int c = 0; c < 4; ++c) acc[r][c] += xv[r] * wv[c];
        }
    }

#pragma unroll
    for (int r = 0; r < 8; ++r) {
        int row = row0 + r0 + r;
        if (row < N_NODES) {
            float dv = dinv[row];
            ushort4 o;
            o.x = f2bf(acc[r][0] * dv);
            o.y = f2bf(acc[r][1] * dv);
            o.z = f2bf(acc[r][2] * dv);
            o.w = f2bf(acc[r][3] * dv);
            *(ushort4*)&outb[(size_t)row * 128 + c0] = o;
        }
    }
}

// ---------------- GEMM2: outb[r][c] = bf16(dinv[r] * (h[N,128] @ W2[128,64])) ----------------
__global__ __launch_bounds__(256) void gemm2_kernel(const float* __restrict__ h,
                                                    const float* __restrict__ W,
                                                    const float* __restrict__ dinv,
                                                    unsigned short* __restrict__ outb) {
    __shared__ float xs[32][128];
    __shared__ float ws[32][64];
    const int tid = threadIdx.x;
    const int row0 = blockIdx.x * 128;
    const int c0 = (tid & 15) * 4;
    const int r0 = (tid >> 4) * 8;

    float acc[8][4];
#pragma unroll
    for (int r = 0; r < 8; ++r)
#pragma unroll
        for (int c = 0; c < 4; ++c) acc[r][c] = 0.f;

    const int lr = tid >> 1;
    const int lk = (tid & 1) * 16;
    int grow = row0 + lr;
    if (grow > N_NODES - 1) grow = N_NODES - 1;
    const float* hrow = h + (size_t)grow * 128;
    const int wk = tid >> 3;
    const int wc = (tid & 7) * 8;

    for (int kc = 0; kc < 4; ++kc) {
        float4 a0 = *(const float4*)&hrow[kc * 32 + lk];
        float4 a1 = *(const float4*)&hrow[kc * 32 + lk + 4];
        float4 a2 = *(const float4*)&hrow[kc * 32 + lk + 8];
        float4 a3 = *(const float4*)&hrow[kc * 32 + lk + 12];
        const float* wsrc = &W[(size_t)(kc * 32 + wk) * 64 + wc];
        float4 w0 = *(const float4*)&wsrc[0];
        float4 w1 = *(const float4*)&wsrc[4];

        if (kc > 0) __syncthreads();
        xs[lk + 0][lr]  = a0.x; xs[lk + 1][lr]  = a0.y;
        xs[lk + 2][lr]  = a0.z; xs[lk + 3][lr]  = a0.w;
        xs[lk + 4][lr]  = a1.x; xs[lk + 5][lr]  = a1.y;
        xs[lk + 6][lr]  = a1.z; xs[lk + 7][lr]  = a1.w;
        xs[lk + 8][lr]  = a2.x; xs[lk + 9][lr]  = a2.y;
        xs[lk + 10][lr] = a2.z; xs[lk + 11][lr] = a2.w;
        xs[lk + 12][lr] = a3.x; xs[lk + 13][lr] = a3.y;
        xs[lk + 14][lr] = a3.z; xs[lk + 15][lr] = a3.w;
        *(float4*)&ws[wk][wc + 0] = w0;
        *(float4*)&ws[wk][wc + 4] = w1;
        __syncthreads();

#pragma unroll 8
        for (int k = 0; k < 32; ++k) {
            float wv[4], xv[8];
            *(float4*)&wv[0] = *(const float4*)&ws[k][c0];
            *(float4*)&xv[0] = *(const float4*)&xs[k][r0];
            *(float4*)&xv[4] = *(const float4*)&xs[k][r0 + 4];
#pragma unroll
            for (int r = 0; r < 8; ++r)
#pragma unroll
                for (int c = 0; c < 4; ++c) acc[r][c] += xv[r] * wv[c];
        }
    }

#pragma unroll
    for (int r = 0; r < 8; ++r) {
        int row = row0 + r0 + r;
        if (row < N_NODES) {
            float dv = dinv[row];
            ushort4 o;
            o.x = f2bf(acc[r][0] * dv);
            o.y = f2bf(acc[r][1] * dv);
            o.z = f2bf(acc[r][2] * dv);
            o.w = f2bf(acc[r][3] * dv);
            *(ushort4*)&outb[(size_t)row * 64 + c0] = o;
        }
    }
}

// ---------------- agg1: h = relu(dinv .* sum(bf16 xw' rows) + b1); F=128 ----------------
// xw' is bf16: one dword (2 bf16) per lane per row. 8-wide gather batches.
__global__ __launch_bounds__(256) void agg1_kernel(const unsigned int* __restrict__ xw,
                                                   const int* __restrict__ csr_src,
                                                   const int* __restrict__ row_ptr,
                                                   const float* __restrict__ dinv,
                                                   const float* __restrict__ bias,
                                                   float* __restrict__ h) {
    const int node = blockIdx.x * 4 + (threadIdx.x >> 6);
    const int lane = threadIdx.x & 63;
    const float2* b2p = (const float2*)bias;
    unsigned int self = xw[(size_t)node * 64 + lane];
    float accx = __uint_as_float(self << 16);
    float accy = __uint_as_float(self & 0xffff0000u);
    const int beg = row_ptr[node], end = row_ptr[node + 1];
    for (int e = beg; e < end; e += 8) {
        int s[8];
        s[0] = csr_src[e];
#pragma unroll
        for (int i = 1; i < 8; ++i)
            s[i] = (e + i < end) ? csr_src[e + i] : s[0];
        unsigned int v[8];
#pragma unroll
        for (int i = 0; i < 8; ++i)
            v[i] = xw[(size_t)s[i] * 64 + lane];
        accx += __uint_as_float(v[0] << 16);
        accy += __uint_as_float(v[0] & 0xffff0000u);
#pragma unroll
        for (int i = 1; i < 8; ++i) {
            if (e + i < end) {
                accx += __uint_as_float(v[i] << 16);
                accy += __uint_as_float(v[i] & 0xffff0000u);
            }
        }
    }
    const float di = dinv[node];
    float2 bv = b2p[lane];
    float v0 = accx * di + bv.x;
    float v1 = accy * di + bv.y;
    float2 o = make_float2(v0 > 0.f ? v0 : 0.f, v1 > 0.f ? v1 : 0.f);
    *(float2*)&h[(size_t)node * 128 + lane * 2] = o;
}

// ---------------- agg2 + mean-pool: F=64 bf16 in, LDS-combined atomics ----------------
__global__ __launch_bounds__(256) void agg2_pool_kernel(const unsigned short* __restrict__ xw,
                                                        const int* __restrict__ csr_src,
                                                        const int* __restrict__ row_ptr,
                                                        const float* __restrict__ dinv,
                                                        const float* __restrict__ bias,
                                                        const int* __restrict__ batch,
                                                        float* __restrict__ gsum,
                                                        float* __restrict__ gcnt) {
    __shared__ float part[4][64];
    __shared__ int bsh[4];
    const int w = threadIdx.x >> 6;
    const int node = blockIdx.x * 4 + w;
    const int lane = threadIdx.x & 63;
    float acc = __uint_as_float((unsigned int)xw[(size_t)node * 64 + lane] << 16);
    const int beg = row_ptr[node], end = row_ptr[node + 1];
    for (int e = beg; e < end; e += 8) {
        int s[8];
        s[0] = csr_src[e];
#pragma unroll
        for (int i = 1; i < 8; ++i)
            s[i] = (e + i < end) ? csr_src[e + i] : s[0];
        unsigned short v[8];
#pragma unroll
        for (int i = 0; i < 8; ++i)
            v[i] = xw[(size_t)s[i] * 64 + lane];
        acc += __uint_as_float((unsigned int)v[0] << 16);
#pragma unroll
        for (int i = 1; i < 8; ++i) {
            if (e + i < end) acc += __uint_as_float((unsigned int)v[i] << 16);
        }
    }
    float val = acc * dinv[node] + bias[lane];
    part[w][lane] = val;
    if (lane == 0) bsh[w] = batch[node];
    __syncthreads();
    if (w == 0) {
        int b0 = bsh[0], b1 = bsh[1], b2 = bsh[2], b3 = bsh[3];
        if (b0 == b1 && b1 == b2 && b2 == b3) {
            float s = part[0][lane] + part[1][lane] + part[2][lane] + part[3][lane];
            atomicAdd(&gsum[b0 * 64 + lane], s);
            if (lane == 0) atomicAdd(&gcnt[b0], 4.0f);
        } else {
            atomicAdd(&gsum[b0 * 64 + lane], part[0][lane]);
            atomicAdd(&gsum[b1 * 64 + lane], part[1][lane]);
            atomicAdd(&gsum[b2 * 64 + lane], part[2][lane]);
            atomicAdd(&gsum[b3 * 64 + lane], part[3][lane]);
            if (lane == 0) {
                atomicAdd(&gcnt[b0], 1.0f);
                atomicAdd(&gcnt[b1], 1.0f);
                atomicAdd(&gcnt[b2], 1.0f);
                atomicAdd(&gcnt[b3], 1.0f);
            }
        }
    }
}

// ---------------- head: mean -> fc -> log_softmax ----------------
__global__ void head_kernel(const float* __restrict__ gsum, const float* __restrict__ gcnt,
                            const float* __restrict__ fcW, const float* __restrict__ fcb,
                            float* __restrict__ out) {
    int g = blockIdx.x * blockDim.x + threadIdx.x;
    if (g >= NUM_GRAPHS) return;
    float c = gcnt[g];
    c = c > 1.f ? c : 1.f;
    float inv = 1.f / c;
    float logits[4];
#pragma unroll
    for (int j = 0; j < 4; ++j) logits[j] = fcb[j];
    for (int k = 0; k < 64; ++k) {
        float m = gsum[g * 64 + k] * inv;
#pragma unroll
        for (int j = 0; j < 4; ++j) logits[j] += m * fcW[k * 4 + j];
    }
    float mx = logits[0];
#pragma unroll
    for (int j = 1; j < 4; ++j) mx = logits[j] > mx ? logits[j] : mx;
    float s = 0.f;
#pragma unroll
    for (int j = 0; j < 4; ++j) s += expf(logits[j] - mx);
    float lse = mx + logf(s);
#pragma unroll
    for (int j = 0; j < 4; ++j) out[g * 4 + j] = logits[j] - lse;
}

extern "C" void kernel_launch(void* const* d_in, const int* in_sizes, int n_in,
                              void* d_out, int out_size, void* d_ws, size_t ws_size,
                              hipStream_t stream) {
    const float* x     = (const float*)d_in[0];
    const int*   ei    = (const int*)d_in[1];     // [2, E]
    const int*   batch = (const int*)d_in[2];
    const float* W1    = (const float*)d_in[3];
    const float* b1    = (const float*)d_in[4];
    const float* W2    = (const float*)d_in[5];
    const float* b2    = (const float*)d_in[6];
    const float* fcW   = (const float*)d_in[7];
    const float* fcb   = (const float*)d_in[8];
    float* out = (float*)d_out;

    const int* src = ei;
    const int* dst = ei + N_EDGES;

    size_t o = 0;
    char* wsb = (char*)d_ws;
    auto take = [&](size_t bytes) -> void* {
        void* p = wsb + o;
        o += (bytes + 255) & ~(size_t)255;
        return p;
    };
    int*   cnt       = (int*)take((size_t)N_NODES * 4);
    float* dinv      = (float*)take((size_t)N_NODES * 4);
    int*   row_ptr   = (int*)take((size_t)(N_NODES + 1) * 4);
    int*   cursor    = (int*)take((size_t)N_NODES * 4);
    int*   csr_src   = (int*)take((size_t)N_EDGES * 4);
    int*   blockSums = (int*)take(1024);
    unsigned short* bufA = (unsigned short*)take((size_t)N_NODES * 128 * 2); // bf16 xw1', later xw2'
    float* bufB      = (float*)take((size_t)N_NODES * 128 * 4);              // h1 (fp32)
    float* gsum      = (float*)take((size_t)NUM_GRAPHS * 64 * 4);
    float* gcnt      = (float*)take((size_t)NUM_GRAPHS * 4);
    (void)ws_size;

    const int TB = 256;

    zero_i32_kernel<<<(N_NODES + TB - 1) / TB, TB, 0, stream>>>(cnt, N_NODES);
    zero_i32_kernel<<<(NUM_GRAPHS * 64 + TB - 1) / TB, TB, 0, stream>>>((int*)gsum, NUM_GRAPHS * 64);
    zero_i32_kernel<<<(NUM_GRAPHS + TB - 1) / TB, TB, 0, stream>>>((int*)gcnt, NUM_GRAPHS);

    count_dst_kernel<<<(N_EDGES + TB - 1) / TB, TB, 0, stream>>>(dst, cnt);
    dinv_kernel<<<(N_NODES + TB - 1) / TB, TB, 0, stream>>>(cnt, dinv);

    scan1_kernel<<<SCAN_NB, SCAN_B, 0, stream>>>(cnt, row_ptr, blockSums);
    scan2_kernel<<<1, 1, 0, stream>>>(blockSums, row_ptr);
    scan3_kernel<<<(N_NODES + TB - 1) / TB, TB, 0, stream>>>(row_ptr, blockSums, cursor);

    // fused: gemm1 (bf16 out) + CSR fill, overlapped
    gemm1_fill_kernel<<<FUSED_BLOCKS, TB, 0, stream>>>(x, W1, dinv, bufA,
                                                       src, dst, cursor, csr_src);

    agg1_kernel<<<N_NODES / 4, TB, 0, stream>>>((const unsigned int*)bufA, csr_src, row_ptr,
                                                dinv, b1, bufB);

    gemm2_kernel<<<(N_NODES + 127) / 128, TB, 0, stream>>>(bufB, W2, dinv, bufA);
    agg2_pool_kernel<<<N_NODES / 4, TB, 0, stream>>>(bufA, csr_src, row_ptr, dinv, b2, batch,
                                                     gsum, gcnt);

    head_kernel<<<(NUM_GRAPHS + TB - 1) / TB, TB, 0, stream>>>(gsum, gcnt, fcW, fcb, out);
}

// Round 5
// 522.694 us; speedup vs baseline: 2.4839x; 1.0129x over previous
//
#include <hip/hip_runtime.h>
#include <hip/hip_bf16.h>

#define N_NODES 100000
#define N_EDGES 1600000
#define NUM_GRAPHS 1000
#define SCAN_B 1024
#define SCAN_NB ((N_NODES + SCAN_B - 1) / SCAN_B)   // 98

#define NODES_PER_BUCKET 512
#define BUCKET_SHIFT 9
#define NBUCKETS 196                                 // ceil(100000/512)

#define G1_BLOCKS 1563            // 100000/64
#define FUSED_BLOCKS 1827         // 7*261: b%7==3 -> bin role (261), else gemm (1566)
#define FILL_CHUNK 6131           // ceil(1.6M/261)

__device__ __forceinline__ unsigned short f2bf(float f) {
    unsigned int u = __float_as_uint(f);
    u = u + 0x7fffu + ((u >> 16) & 1u);      // round-to-nearest-even
    return (unsigned short)(u >> 16);
}

// ---------------- utility ----------------
__global__ void zero_i32_kernel(int* __restrict__ p, int n) {
    int i = blockIdx.x * blockDim.x + threadIdx.x;
    if (i < n) p[i] = 0;
}

// ---------------- degree / dinv ----------------
__global__ void count_dst_kernel(const int* __restrict__ dst, int* __restrict__ cnt) {
    int e = blockIdx.x * blockDim.x + threadIdx.x;
    if (e < N_EDGES) atomicAdd(&cnt[dst[e]], 1);
}

__global__ void dinv_kernel(const int* __restrict__ cnt, float* __restrict__ dinv) {
    int i = blockIdx.x * blockDim.x + threadIdx.x;
    if (i < N_NODES) dinv[i] = rsqrtf((float)(cnt[i] + 1));  // +1 self loop
}

// ---------------- exclusive scan (row_ptr) ----------------
__global__ void scan1_kernel(const int* __restrict__ cnt, int* __restrict__ row_ptr,
                             int* __restrict__ blockSums) {
    __shared__ int sh[SCAN_B];
    int t = threadIdx.x;
    int i = blockIdx.x * SCAN_B + t;
    int v = (i < N_NODES) ? cnt[i] : 0;
    sh[t] = v;
    for (int off = 1; off < SCAN_B; off <<= 1) {
        __syncthreads();
        int add = (t >= off) ? sh[t - off] : 0;
        __syncthreads();
        sh[t] += add;
    }
    if (i < N_NODES) row_ptr[i] = sh[t] - v;
    if (t == SCAN_B - 1) blockSums[blockIdx.x] = sh[t];
}

__global__ void scan2_kernel(int* __restrict__ blockSums, int* __restrict__ row_ptr) {
    if (threadIdx.x == 0 && blockIdx.x == 0) {
        int run = 0;
        for (int b = 0; b < SCAN_NB; ++b) { int s = blockSums[b]; blockSums[b] = run; run += s; }
        row_ptr[N_NODES] = run;
    }
}

// also initializes per-bucket bin cursors (bcursor[b] = row_ptr[b*512])
__global__ void scan3_kernel(int* __restrict__ row_ptr, const int* __restrict__ blockSums,
                             int* __restrict__ bcursor) {
    int i = blockIdx.x * blockDim.x + threadIdx.x;
    if (i < N_NODES) {
        int v = row_ptr[i] + blockSums[i / SCAN_B];
        row_ptr[i] = v;
        if ((i & (NODES_PER_BUCKET - 1)) == 0) bcursor[i >> BUCKET_SHIFT] = v;
    }
}

// ---------------- fused: GEMM1 (bf16 out) + edge binning (phase B1) ----------------
// role: blockIdx%7==3 -> bin chunk of edges into dst-buckets; else gemm tile.
__global__ __launch_bounds__(256) void gemm1_fill_kernel(const float* __restrict__ x,
                                                         const float* __restrict__ W,
                                                         const float* __restrict__ dinv,
                                                         unsigned short* __restrict__ outb,
                                                         const int* __restrict__ esrc,
                                                         const int* __restrict__ edst,
                                                         int* __restrict__ bcursor,
                                                         int2* __restrict__ pairs) {
    __shared__ float xs[32][66];     // stride 66: staging writes 2-way (free)
    __shared__ float ws[32][132];    // stride 132: staging writes 2-way (free)
    const int b = blockIdx.x;
    const int tid = threadIdx.x;

    if (b % 7 == 3) {
        // ---- bin role: scatter (src,dst) into bucket-grouped pairs array ----
        int* scnt = (int*)&xs[0][0];           // NBUCKETS counters
        int* spos = scnt + 256;                // NBUCKETS cursors
        const int fid = b / 7;
        const int beg = fid * FILL_CHUNK;
        int end = beg + FILL_CHUNK;
        if (end > N_EDGES) end = N_EDGES;
        if (tid < NBUCKETS) scnt[tid] = 0;
        __syncthreads();
        for (int e = beg + tid; e < end; e += 256)
            atomicAdd(&scnt[edst[e] >> BUCKET_SHIFT], 1);
        __syncthreads();
        if (tid < NBUCKETS) {
            int c = scnt[tid];
            spos[tid] = c > 0 ? atomicAdd(&bcursor[tid], c) : 0;
        }
        __syncthreads();
        for (int e = beg + tid; e < end; e += 256) {
            int d = edst[e];
            int s = esrc[e];
            int p = atomicAdd(&spos[d >> BUCKET_SHIFT], 1);
            pairs[p] = make_int2(s, d);
        }
        return;
    }

    // ---- GEMM role ----
    const int b7 = b % 7;
    const int gid = (b / 7) * 6 + b7 - (b7 > 3 ? 1 : 0);
    if (gid >= G1_BLOCKS) return;
    const int row0 = gid * 64;
    const int c0 = (tid & 31) * 4;
    const int r0 = (tid >> 5) * 8;

    float acc[8][4];
#pragma unroll
    for (int r = 0; r < 8; ++r)
#pragma unroll
        for (int c = 0; c < 4; ++c) acc[r][c] = 0.f;

    const int lr = tid >> 2;
    const int lk = (tid & 3) * 8;
    int grow = row0 + lr;
    if (grow > N_NODES - 1) grow = N_NODES - 1;
    const float* xrow = x + (size_t)grow * 256;
    const int wk = tid >> 3;
    const int wc = (tid & 7) * 16;

    for (int kc = 0; kc < 8; ++kc) {
        float4 a0 = *(const float4*)&xrow[kc * 32 + lk];
        float4 a1 = *(const float4*)&xrow[kc * 32 + lk + 4];
        const float* wsrc = &W[(size_t)(kc * 32 + wk) * 128 + wc];
        float4 w0 = *(const float4*)&wsrc[0];
        float4 w1 = *(const float4*)&wsrc[4];
        float4 w2 = *(const float4*)&wsrc[8];
        float4 w3 = *(const float4*)&wsrc[12];

        if (kc > 0) __syncthreads();
        xs[lk + 0][lr] = a0.x; xs[lk + 1][lr] = a0.y;
        xs[lk + 2][lr] = a0.z; xs[lk + 3][lr] = a0.w;
        xs[lk + 4][lr] = a1.x; xs[lk + 5][lr] = a1.y;
        xs[lk + 6][lr] = a1.z; xs[lk + 7][lr] = a1.w;
        *(float4*)&ws[wk][wc + 0]  = w0;
        *(float4*)&ws[wk][wc + 4]  = w1;
        *(float4*)&ws[wk][wc + 8]  = w2;
        *(float4*)&ws[wk][wc + 12] = w3;
        __syncthreads();

#pragma unroll 8
        for (int k = 0; k < 32; ++k) {
            float wv[4], xv[8];
            *(float4*)&wv[0] = *(const float4*)&ws[k][c0];
            *(float2*)&xv[0] = *(const float2*)&xs[k][r0];
            *(float2*)&xv[2] = *(const float2*)&xs[k][r0 + 2];
            *(float2*)&xv[4] = *(const float2*)&xs[k][r0 + 4];
            *(float2*)&xv[6] = *(const float2*)&xs[k][r0 + 6];
#pragma unroll
            for (int r = 0; r < 8; ++r)
#pragma unroll
                for (int c = 0; c < 4; ++c) acc[r][c] += xv[r] * wv[c];
        }
    }

#pragma unroll
    for (int r = 0; r < 8; ++r) {
        int row = row0 + r0 + r;
        if (row < N_NODES) {
            float dv = dinv[row];
            ushort4 o;
            o.x = f2bf(acc[r][0] * dv);
            o.y = f2bf(acc[r][1] * dv);
            o.z = f2bf(acc[r][2] * dv);
            o.w = f2bf(acc[r][3] * dv);
            *(ushort4*)&outb[(size_t)row * 128 + c0] = o;
        }
    }
}

// ---------------- phase B2: per-bucket local CSR fill ----------------
// One block per bucket; csr region for a bucket is written by exactly one block (one XCD).
__global__ __launch_bounds__(256) void csr_fill_local_kernel(const int2* __restrict__ pairs,
                                                             const int* __restrict__ row_ptr,
                                                             int* __restrict__ csr_src) {
    __shared__ int cur[NODES_PER_BUCKET];
    const int b = blockIdx.x;
    const int n0 = b * NODES_PER_BUCKET;
    int n1 = n0 + NODES_PER_BUCKET;
    if (n1 > N_NODES) n1 = N_NODES;
    const int tid = threadIdx.x;
    for (int i = tid; i < n1 - n0; i += 256) cur[i] = row_ptr[n0 + i];
    __syncthreads();
    const int pbeg = row_ptr[n0];
    const int pend = row_ptr[n1];
    for (int p = pbeg + tid; p < pend; p += 256) {
        int2 pr = pairs[p];
        int pos = atomicAdd(&cur[pr.y - n0], 1);
        csr_src[pos] = pr.x;
    }
}

// ---------------- GEMM2: outb[r][c] = bf16(dinv[r] * (h[N,128] @ W2[128,64])) ----------------
__global__ __launch_bounds__(256) void gemm2_kernel(const float* __restrict__ h,
                                                    const float* __restrict__ W,
                                                    const float* __restrict__ dinv,
                                                    unsigned short* __restrict__ outb) {
    __shared__ float xs[32][128];
    __shared__ float ws[32][64];
    const int tid = threadIdx.x;
    const int row0 = blockIdx.x * 128;
    const int c0 = (tid & 15) * 4;
    const int r0 = (tid >> 4) * 8;

    float acc[8][4];
#pragma unroll
    for (int r = 0; r < 8; ++r)
#pragma unroll
        for (int c = 0; c < 4; ++c) acc[r][c] = 0.f;

    const int lr = tid >> 1;
    const int lk = (tid & 1) * 16;
    int grow = row0 + lr;
    if (grow > N_NODES - 1) grow = N_NODES - 1;
    const float* hrow = h + (size_t)grow * 128;
    const int wk = tid >> 3;
    const int wc = (tid & 7) * 8;

    for (int kc = 0; kc < 4; ++kc) {
        float4 a0 = *(const float4*)&hrow[kc * 32 + lk];
        float4 a1 = *(const float4*)&hrow[kc * 32 + lk + 4];
        float4 a2 = *(const float4*)&hrow[kc * 32 + lk + 8];
        float4 a3 = *(const float4*)&hrow[kc * 32 + lk + 12];
        const float* wsrc = &W[(size_t)(kc * 32 + wk) * 64 + wc];
        float4 w0 = *(const float4*)&wsrc[0];
        float4 w1 = *(const float4*)&wsrc[4];

        if (kc > 0) __syncthreads();
        xs[lk + 0][lr]  = a0.x; xs[lk + 1][lr]  = a0.y;
        xs[lk + 2][lr]  = a0.z; xs[lk + 3][lr]  = a0.w;
        xs[lk + 4][lr]  = a1.x; xs[lk + 5][lr]  = a1.y;
        xs[lk + 6][lr]  = a1.z; xs[lk + 7][lr]  = a1.w;
        xs[lk + 8][lr]  = a2.x; xs[lk + 9][lr]  = a2.y;
        xs[lk + 10][lr] = a2.z; xs[lk + 11][lr] = a2.w;
        xs[lk + 12][lr] = a3.x; xs[lk + 13][lr] = a3.y;
        xs[lk + 14][lr] = a3.z; xs[lk + 15][lr] = a3.w;
        *(float4*)&ws[wk][wc + 0] = w0;
        *(float4*)&ws[wk][wc + 4] = w1;
        __syncthreads();

#pragma unroll 8
        for (int k = 0; k < 32; ++k) {
            float wv[4], xv[8];
            *(float4*)&wv[0] = *(const float4*)&ws[k][c0];
            *(float4*)&xv[0] = *(const float4*)&xs[k][r0];
            *(float4*)&xv[4] = *(const float4*)&xs[k][r0 + 4];
#pragma unroll
            for (int r = 0; r < 8; ++r)
#pragma unroll
                for (int c = 0; c < 4; ++c) acc[r][c] += xv[r] * wv[c];
        }
    }

#pragma unroll
    for (int r = 0; r < 8; ++r) {
        int row = row0 + r0 + r;
        if (row < N_NODES) {
            float dv = dinv[row];
            ushort4 o;
            o.x = f2bf(acc[r][0] * dv);
            o.y = f2bf(acc[r][1] * dv);
            o.z = f2bf(acc[r][2] * dv);
            o.w = f2bf(acc[r][3] * dv);
            *(ushort4*)&outb[(size_t)row * 64 + c0] = o;
        }
    }
}

// ---------------- agg1: h = relu(dinv .* sum(bf16 xw' rows) + b1); F=128 ----------------
__global__ __launch_bounds__(256) void agg1_kernel(const unsigned int* __restrict__ xw,
                                                   const int* __restrict__ csr_src,
                                                   const int* __restrict__ row_ptr,
                                                   const float* __restrict__ dinv,
                                                   const float* __restrict__ bias,
                                                   float* __restrict__ h) {
    const int node = blockIdx.x * 4 + (threadIdx.x >> 6);
    const int lane = threadIdx.x & 63;
    const float2* b2p = (const float2*)bias;
    unsigned int self = xw[(size_t)node * 64 + lane];
    float accx = __uint_as_float(self << 16);
    float accy = __uint_as_float(self & 0xffff0000u);
    const int beg = row_ptr[node], end = row_ptr[node + 1];
    for (int e = beg; e < end; e += 8) {
        int s[8];
        s[0] = csr_src[e];
#pragma unroll
        for (int i = 1; i < 8; ++i)
            s[i] = (e + i < end) ? csr_src[e + i] : s[0];
        unsigned int v[8];
#pragma unroll
        for (int i = 0; i < 8; ++i)
            v[i] = xw[(size_t)s[i] * 64 + lane];
        accx += __uint_as_float(v[0] << 16);
        accy += __uint_as_float(v[0] & 0xffff0000u);
#pragma unroll
        for (int i = 1; i < 8; ++i) {
            if (e + i < end) {
                accx += __uint_as_float(v[i] << 16);
                accy += __uint_as_float(v[i] & 0xffff0000u);
            }
        }
    }
    const float di = dinv[node];
    float2 bv = b2p[lane];
    float v0 = accx * di + bv.x;
    float v1 = accy * di + bv.y;
    float2 o = make_float2(v0 > 0.f ? v0 : 0.f, v1 > 0.f ? v1 : 0.f);
    *(float2*)&h[(size_t)node * 128 + lane * 2] = o;
}

// ---------------- agg2 + mean-pool: F=64 bf16 in, LDS-combined atomics ----------------
__global__ __launch_bounds__(256) void agg2_pool_kernel(const unsigned short* __restrict__ xw,
                                                        const int* __restrict__ csr_src,
                                                        const int* __restrict__ row_ptr,
                                                        const float* __restrict__ dinv,
                                                        const float* __restrict__ bias,
                                                        const int* __restrict__ batch,
                                                        float* __restrict__ gsum,
                                                        float* __restrict__ gcnt) {
    __shared__ float part[4][64];
    __shared__ int bsh[4];
    const int w = threadIdx.x >> 6;
    const int node = blockIdx.x * 4 + w;
    const int lane = threadIdx.x & 63;
    float acc = __uint_as_float((unsigned int)xw[(size_t)node * 64 + lane] << 16);
    const int beg = row_ptr[node], end = row_ptr[node + 1];
    for (int e = beg; e < end; e += 8) {
        int s[8];
        s[0] = csr_src[e];
#pragma unroll
        for (int i = 1; i < 8; ++i)
            s[i] = (e + i < end) ? csr_src[e + i] : s[0];
        unsigned short v[8];
#pragma unroll
        for (int i = 0; i < 8; ++i)
            v[i] = xw[(size_t)s[i] * 64 + lane];
        acc += __uint_as_float((unsigned int)v[0] << 16);
#pragma unroll
        for (int i = 1; i < 8; ++i) {
            if (e + i < end) acc += __uint_as_float((unsigned int)v[i] << 16);
        }
    }
    float val = acc * dinv[node] + bias[lane];
    part[w][lane] = val;
    if (lane == 0) bsh[w] = batch[node];
    __syncthreads();
    if (w == 0) {
        int b0 = bsh[0], b1 = bsh[1], b2 = bsh[2], b3 = bsh[3];
        if (b0 == b1 && b1 == b2 && b2 == b3) {
            float s = part[0][lane] + part[1][lane] + part[2][lane] + part[3][lane];
            atomicAdd(&gsum[b0 * 64 + lane], s);
            if (lane == 0) atomicAdd(&gcnt[b0], 4.0f);
        } else {
            atomicAdd(&gsum[b0 * 64 + lane], part[0][lane]);
            atomicAdd(&gsum[b1 * 64 + lane], part[1][lane]);
            atomicAdd(&gsum[b2 * 64 + lane], part[2][lane]);
            atomicAdd(&gsum[b3 * 64 + lane], part[3][lane]);
            if (lane == 0) {
                atomicAdd(&gcnt[b0], 1.0f);
                atomicAdd(&gcnt[b1], 1.0f);
                atomicAdd(&gcnt[b2], 1.0f);
                atomicAdd(&gcnt[b3], 1.0f);
            }
        }
    }
}

// ---------------- head: mean -> fc -> log_softmax ----------------
__global__ void head_kernel(const float* __restrict__ gsum, const float* __restrict__ gcnt,
                            const float* __restrict__ fcW, const float* __restrict__ fcb,
                            float* __restrict__ out) {
    int g = blockIdx.x * blockDim.x + threadIdx.x;
    if (g >= NUM_GRAPHS) return;
    float c = gcnt[g];
    c = c > 1.f ? c : 1.f;
    float inv = 1.f / c;
    float logits[4];
#pragma unroll
    for (int j = 0; j < 4; ++j) logits[j] = fcb[j];
    for (int k = 0; k < 64; ++k) {
        float m = gsum[g * 64 + k] * inv;
#pragma unroll
        for (int j = 0; j < 4; ++j) logits[j] += m * fcW[k * 4 + j];
    }
    float mx = logits[0];
#pragma unroll
    for (int j = 1; j < 4; ++j) mx = logits[j] > mx ? logits[j] : mx;
    float s = 0.f;
#pragma unroll
    for (int j = 0; j < 4; ++j) s += expf(logits[j] - mx);
    float lse = mx + logf(s);
#pragma unroll
    for (int j = 0; j < 4; ++j) out[g * 4 + j] = logits[j] - lse;
}

extern "C" void kernel_launch(void* const* d_in, const int* in_sizes, int n_in,
                              void* d_out, int out_size, void* d_ws, size_t ws_size,
                              hipStream_t stream) {
    const float* x     = (const float*)d_in[0];
    const int*   ei    = (const int*)d_in[1];     // [2, E]
    const int*   batch = (const int*)d_in[2];
    const float* W1    = (const float*)d_in[3];
    const float* b1    = (const float*)d_in[4];
    const float* W2    = (const float*)d_in[5];
    const float* b2    = (const float*)d_in[6];
    const float* fcW   = (const float*)d_in[7];
    const float* fcb   = (const float*)d_in[8];
    float* out = (float*)d_out;

    const int* src = ei;
    const int* dst = ei + N_EDGES;

    size_t o = 0;
    char* wsb = (char*)d_ws;
    auto take = [&](size_t bytes) -> void* {
        void* p = wsb + o;
        o += (bytes + 255) & ~(size_t)255;
        return p;
    };
    int*   cnt       = (int*)take((size_t)N_NODES * 4);
    float* dinv      = (float*)take((size_t)N_NODES * 4);
    int*   row_ptr   = (int*)take((size_t)(N_NODES + 1) * 4);
    int*   bcursor   = (int*)take((size_t)NBUCKETS * 4);
    int*   csr_src   = (int*)take((size_t)N_EDGES * 4);
    int2*  pairs     = (int2*)take((size_t)N_EDGES * 8);
    int*   blockSums = (int*)take(1024);
    unsigned short* bufA = (unsigned short*)take((size_t)N_NODES * 128 * 2); // bf16 xw1'/xw2'
    float* bufB      = (float*)take((size_t)N_NODES * 128 * 4);              // h1 (fp32)
    float* gsum      = (float*)take((size_t)NUM_GRAPHS * 64 * 4);
    float* gcnt      = (float*)take((size_t)NUM_GRAPHS * 4);
    (void)ws_size;

    const int TB = 256;

    zero_i32_kernel<<<(N_NODES + TB - 1) / TB, TB, 0, stream>>>(cnt, N_NODES);
    zero_i32_kernel<<<(NUM_GRAPHS * 64 + TB - 1) / TB, TB, 0, stream>>>((int*)gsum, NUM_GRAPHS * 64);
    zero_i32_kernel<<<(NUM_GRAPHS + TB - 1) / TB, TB, 0, stream>>>((int*)gcnt, NUM_GRAPHS);

    count_dst_kernel<<<(N_EDGES + TB - 1) / TB, TB, 0, stream>>>(dst, cnt);
    dinv_kernel<<<(N_NODES + TB - 1) / TB, TB, 0, stream>>>(cnt, dinv);

    scan1_kernel<<<SCAN_NB, SCAN_B, 0, stream>>>(cnt, row_ptr, blockSums);
    scan2_kernel<<<1, 1, 0, stream>>>(blockSums, row_ptr);
    scan3_kernel<<<(N_NODES + TB - 1) / TB, TB, 0, stream>>>(row_ptr, blockSums, bcursor);

    // fused: gemm1 (bf16 out) + edge binning (B1)
    gemm1_fill_kernel<<<FUSED_BLOCKS, TB, 0, stream>>>(x, W1, dinv, bufA,
                                                       src, dst, bcursor, pairs);

    // B2: per-bucket local CSR fill (single-XCD write regions)
    csr_fill_local_kernel<<<NBUCKETS, TB, 0, stream>>>(pairs, row_ptr, csr_src);

    agg1_kernel<<<N_NODES / 4, TB, 0, stream>>>((const unsigned int*)bufA, csr_src, row_ptr,
                                                dinv, b1, bufB);

    gemm2_kernel<<<(N_NODES + 127) / 128, TB, 0, stream>>>(bufB, W2, dinv, bufA);
    agg2_pool_kernel<<<N_NODES / 4, TB, 0, stream>>>(bufA, csr_src, row_ptr, dinv, b2, batch,
                                                     gsum, gcnt);

    head_kernel<<<(NUM_GRAPHS + TB - 1) / TB, TB, 0, stream>>>(gsum, gcnt, fcW, fcb, out);
}

// Round 6
// 494.639 us; speedup vs baseline: 2.6248x; 1.0567x over previous
//
#include <hip/hip_runtime.h>
#include <hip/hip_bf16.h>

#define N_NODES 100000
#define N_EDGES 1600000
#define NUM_GRAPHS 1000
#define SCAN_B 1024
#define SCAN_NB ((N_NODES + SCAN_B - 1) / SCAN_B)   // 98

#define NODES_PER_BUCKET 256
#define BUCKET_SHIFT 8
#define NBUCKETS 391                                 // ceil(100000/256)

#define G1_BLOCKS 1563            // 100000/64
#define FUSED_BLOCKS 2084         // b%4==3 -> bin (521), else gemm (1563)
#define FILL_CHUNK 3072           // ceil(1.6M/521)

typedef __attribute__((ext_vector_type(8))) short short8;
typedef __attribute__((ext_vector_type(4))) float f32x4;
typedef unsigned short ushort;

__device__ __forceinline__ ushort f2bf(float f) {
    unsigned int u = __float_as_uint(f);
    u = u + 0x7fffu + ((u >> 16) & 1u);      // round-to-nearest-even
    return (ushort)(u >> 16);
}

// ---------------- utility ----------------
__global__ void zero_i32_kernel(int* __restrict__ p, int n) {
    int i = blockIdx.x * blockDim.x + threadIdx.x;
    if (i < n) p[i] = 0;
}

// ---------------- W1 -> bf16 transposed [128][256] ----------------
__global__ void prep_w1t_kernel(const float* __restrict__ W1, ushort* __restrict__ W1t) {
    int idx = blockIdx.x * 256 + threadIdx.x;    // 32768
    int n = idx & 127, k = idx >> 7;
    W1t[n * 256 + k] = f2bf(W1[k * 128 + n]);    // coalesced read
}

// ---------------- degree / dinv ----------------
__global__ void count_dst_kernel(const int* __restrict__ dst, int* __restrict__ cnt) {
    int e = blockIdx.x * blockDim.x + threadIdx.x;
    if (e < N_EDGES) atomicAdd(&cnt[dst[e]], 1);
}

__global__ void dinv_kernel(const int* __restrict__ cnt, float* __restrict__ dinv) {
    int i = blockIdx.x * blockDim.x + threadIdx.x;
    if (i < N_NODES) dinv[i] = rsqrtf((float)(cnt[i] + 1));  // +1 self loop
}

// ---------------- exclusive scan (row_ptr) ----------------
__global__ void scan1_kernel(const int* __restrict__ cnt, int* __restrict__ row_ptr,
                             int* __restrict__ blockSums) {
    __shared__ int sh[SCAN_B];
    int t = threadIdx.x;
    int i = blockIdx.x * SCAN_B + t;
    int v = (i < N_NODES) ? cnt[i] : 0;
    sh[t] = v;
    for (int off = 1; off < SCAN_B; off <<= 1) {
        __syncthreads();
        int add = (t >= off) ? sh[t - off] : 0;
        __syncthreads();
        sh[t] += add;
    }
    if (i < N_NODES) row_ptr[i] = sh[t] - v;
    if (t == SCAN_B - 1) blockSums[blockIdx.x] = sh[t];
}

// parallel 128-wide scan of block sums
__global__ void scan2_kernel(int* __restrict__ blockSums, int* __restrict__ row_ptr) {
    __shared__ int sh[128];
    int t = threadIdx.x;                       // 128 threads
    int v = (t < SCAN_NB) ? blockSums[t] : 0;
    sh[t] = v;
    for (int off = 1; off < 128; off <<= 1) {
        __syncthreads();
        int add = (t >= off) ? sh[t - off] : 0;
        __syncthreads();
        sh[t] += add;
    }
    __syncthreads();
    if (t < SCAN_NB) blockSums[t] = sh[t] - v;  // exclusive
    if (t == SCAN_NB - 1) row_ptr[N_NODES] = sh[t];
}

// also initializes per-bucket bin cursors
__global__ void scan3_kernel(int* __restrict__ row_ptr, const int* __restrict__ blockSums,
                             int* __restrict__ bcursor) {
    int i = blockIdx.x * blockDim.x + threadIdx.x;
    if (i < N_NODES) {
        int v = row_ptr[i] + blockSums[i / SCAN_B];
        row_ptr[i] = v;
        if ((i & (NODES_PER_BUCKET - 1)) == 0) bcursor[i >> BUCKET_SHIFT] = v;
    }
}

// ---------------- fused: GEMM1 via bf16 MFMA + edge binning ----------------
// gemm: outb = bf16(dinv[r] * (x @ W1)); 64 rows x 128 cols per block, K=256 in 8 chunks of 32.
// bin: scatter (src,dst) into bucket-grouped pairs.
__global__ __launch_bounds__(256) void gemm1_fill_kernel(const float* __restrict__ x,
                                                         const ushort* __restrict__ W1t,
                                                         const float* __restrict__ dinv,
                                                         ushort* __restrict__ outb,
                                                         const int* __restrict__ esrc,
                                                         const int* __restrict__ edst,
                                                         int* __restrict__ bcursor,
                                                         int2* __restrict__ pairs) {
    __shared__ ushort Ab[64 * 32];    // [row][k] bf16, 4 KB
    __shared__ ushort Bb[128 * 32];   // [n][k] bf16 (W1 transposed), 8 KB
    const int b = blockIdx.x;
    const int tid = threadIdx.x;

    if ((b & 3) == 3) {
        // ---- bin role ----
        int* scnt = (int*)Ab;                   // NBUCKETS counters
        int* spos = (int*)Bb;                   // NBUCKETS cursors
        const int fid = b >> 2;
        const int beg = fid * FILL_CHUNK;
        int end = beg + FILL_CHUNK;
        if (end > N_EDGES) end = N_EDGES;
        for (int i = tid; i < NBUCKETS; i += 256) scnt[i] = 0;
        __syncthreads();
        for (int e = beg + tid; e < end; e += 256)
            atomicAdd(&scnt[edst[e] >> BUCKET_SHIFT], 1);
        __syncthreads();
        for (int i = tid; i < NBUCKETS; i += 256) {
            int c = scnt[i];
            spos[i] = c > 0 ? atomicAdd(&bcursor[i], c) : 0;
        }
        __syncthreads();
        for (int e = beg + tid; e < end; e += 256) {
            int d = edst[e];
            int s = esrc[e];
            int p = atomicAdd(&spos[d >> BUCKET_SHIFT], 1);
            pairs[p] = make_int2(s, d);
        }
        return;
    }

    // ---- GEMM role (MFMA) ----
    const int gid = b - (b >> 2);
    const int row0 = gid * 64;
    const int wv = tid >> 6;                   // wave 0..3 -> rows wv*16..+15
    const int l = tid & 63;
    const int lrow = l & 15;
    const int quad = l >> 4;

    // staging assignments
    const int ar = tid >> 2;                   // 0..63 tile row
    const int ak = (tid & 3) * 8;              // k offset
    int grow = row0 + ar;
    if (grow > N_NODES - 1) grow = N_NODES - 1;
    const float* xrow = x + (size_t)grow * 256;
    const int bn = tid >> 1;                   // 0..127 col
    const int bk = (tid & 1) * 16;             // k offset

    f32x4 acc[8];
#pragma unroll
    for (int t = 0; t < 8; ++t) acc[t] = (f32x4){0.f, 0.f, 0.f, 0.f};

    for (int kc = 0; kc < 8; ++kc) {
        float4 a0 = *(const float4*)&xrow[kc * 32 + ak];
        float4 a1 = *(const float4*)&xrow[kc * 32 + ak + 4];
        const ushort* wt = &W1t[(size_t)bn * 256 + kc * 32 + bk];
        uint4 w0 = *(const uint4*)wt;          // 8 bf16
        uint4 w1 = *(const uint4*)(wt + 8);    // 8 bf16

        if (kc > 0) __syncthreads();
        ushort av[8];
        av[0] = f2bf(a0.x); av[1] = f2bf(a0.y); av[2] = f2bf(a0.z); av[3] = f2bf(a0.w);
        av[4] = f2bf(a1.x); av[5] = f2bf(a1.y); av[6] = f2bf(a1.z); av[7] = f2bf(a1.w);
        *(uint4*)&Ab[ar * 32 + ak] = *(uint4*)av;
        *(uint4*)&Bb[bn * 32 + bk] = w0;
        *(uint4*)&Bb[bn * 32 + bk + 8] = w1;
        __syncthreads();

        short8 afrag = *(const short8*)&Ab[(wv * 16 + lrow) * 32 + quad * 8];
#pragma unroll
        for (int t = 0; t < 8; ++t) {
            short8 bfrag = *(const short8*)&Bb[(t * 16 + lrow) * 32 + quad * 8];
            acc[t] = __builtin_amdgcn_mfma_f32_16x16x32_bf16(afrag, bfrag, acc[t], 0, 0, 0);
        }
    }

    // epilogue: C/D layout col=lane&15, row=quad*4+reg
    const int rbase = row0 + wv * 16 + quad * 4;
    float dv[4];
#pragma unroll
    for (int r = 0; r < 4; ++r) {
        int rr = rbase + r;
        dv[r] = (rr < N_NODES) ? dinv[rr] : 0.f;
    }
#pragma unroll
    for (int t = 0; t < 8; ++t) {
#pragma unroll
        for (int r = 0; r < 4; ++r) {
            int row = rbase + r;
            if (row < N_NODES)
                outb[(size_t)row * 128 + t * 16 + lrow] = f2bf(acc[t][r] * dv[r]);
        }
    }
}

// ---------------- per-bucket local CSR fill ----------------
__global__ __launch_bounds__(256) void csr_fill_local_kernel(const int2* __restrict__ pairs,
                                                             const int* __restrict__ row_ptr,
                                                             int* __restrict__ csr_src) {
    __shared__ int cur[NODES_PER_BUCKET];
    const int b = blockIdx.x;
    const int n0 = b * NODES_PER_BUCKET;
    int n1 = n0 + NODES_PER_BUCKET;
    if (n1 > N_NODES) n1 = N_NODES;
    const int tid = threadIdx.x;
    for (int i = tid; i < n1 - n0; i += 256) cur[i] = row_ptr[n0 + i];
    __syncthreads();
    const int pbeg = row_ptr[n0];
    const int pend = row_ptr[n1];
    for (int p = pbeg + tid; p < pend; p += 256) {
        int2 pr = pairs[p];
        int pos = atomicAdd(&cur[pr.y - n0], 1);
        csr_src[pos] = pr.x;
    }
}

// ---------------- GEMM2: outb = bf16(dinv[r] * (h[N,128] @ W2[128,64])) ----------------
__global__ __launch_bounds__(256) void gemm2_kernel(const float* __restrict__ h,
                                                    const float* __restrict__ W,
                                                    const float* __restrict__ dinv,
                                                    ushort* __restrict__ outb) {
    __shared__ float xs[32][128];
    __shared__ float ws[32][64];
    const int tid = threadIdx.x;
    const int row0 = blockIdx.x * 128;
    const int c0 = (tid & 15) * 4;
    const int r0 = (tid >> 4) * 8;

    float acc[8][4];
#pragma unroll
    for (int r = 0; r < 8; ++r)
#pragma unroll
        for (int c = 0; c < 4; ++c) acc[r][c] = 0.f;

    const int lr = tid >> 1;
    const int lk = (tid & 1) * 16;
    int grow = row0 + lr;
    if (grow > N_NODES - 1) grow = N_NODES - 1;
    const float* hrow = h + (size_t)grow * 128;
    const int wk = tid >> 3;
    const int wc = (tid & 7) * 8;

    for (int kc = 0; kc < 4; ++kc) {
        float4 a0 = *(const float4*)&hrow[kc * 32 + lk];
        float4 a1 = *(const float4*)&hrow[kc * 32 + lk + 4];
        float4 a2 = *(const float4*)&hrow[kc * 32 + lk + 8];
        float4 a3 = *(const float4*)&hrow[kc * 32 + lk + 12];
        const float* wsrc = &W[(size_t)(kc * 32 + wk) * 64 + wc];
        float4 w0 = *(const float4*)&wsrc[0];
        float4 w1 = *(const float4*)&wsrc[4];

        if (kc > 0) __syncthreads();
        xs[lk + 0][lr]  = a0.x; xs[lk + 1][lr]  = a0.y;
        xs[lk + 2][lr]  = a0.z; xs[lk + 3][lr]  = a0.w;
        xs[lk + 4][lr]  = a1.x; xs[lk + 5][lr]  = a1.y;
        xs[lk + 6][lr]  = a1.z; xs[lk + 7][lr]  = a1.w;
        xs[lk + 8][lr]  = a2.x; xs[lk + 9][lr]  = a2.y;
        xs[lk + 10][lr] = a2.z; xs[lk + 11][lr] = a2.w;
        xs[lk + 12][lr] = a3.x; xs[lk + 13][lr] = a3.y;
        xs[lk + 14][lr] = a3.z; xs[lk + 15][lr] = a3.w;
        *(float4*)&ws[wk][wc + 0] = w0;
        *(float4*)&ws[wk][wc + 4] = w1;
        __syncthreads();

#pragma unroll 8
        for (int k = 0; k < 32; ++k) {
            float wvv[4], xv[8];
            *(float4*)&wvv[0] = *(const float4*)&ws[k][c0];
            *(float4*)&xv[0] = *(const float4*)&xs[k][r0];
            *(float4*)&xv[4] = *(const float4*)&xs[k][r0 + 4];
#pragma unroll
            for (int r = 0; r < 8; ++r)
#pragma unroll
                for (int c = 0; c < 4; ++c) acc[r][c] += xv[r] * wvv[c];
        }
    }

#pragma unroll
    for (int r = 0; r < 8; ++r) {
        int row = row0 + r0 + r;
        if (row < N_NODES) {
            float dvv = dinv[row];
            ushort4 o;
            o.x = f2bf(acc[r][0] * dvv);
            o.y = f2bf(acc[r][1] * dvv);
            o.z = f2bf(acc[r][2] * dvv);
            o.w = f2bf(acc[r][3] * dvv);
            *(ushort4*)&outb[(size_t)row * 64 + c0] = o;
        }
    }
}

// ---------------- agg1: h = relu(dinv .* sum(bf16 xw' rows) + b1); F=128 ----------------
// 16-wide predicated gather batches.
__global__ __launch_bounds__(256) void agg1_kernel(const unsigned int* __restrict__ xw,
                                                   const int* __restrict__ csr_src,
                                                   const int* __restrict__ row_ptr,
                                                   const float* __restrict__ dinv,
                                                   const float* __restrict__ bias,
                                                   float* __restrict__ h) {
    const int node = blockIdx.x * 4 + (threadIdx.x >> 6);
    const int lane = threadIdx.x & 63;
    const float2* b2p = (const float2*)bias;
    unsigned int self = xw[(size_t)node * 64 + lane];
    float accx = __uint_as_float(self << 16);
    float accy = __uint_as_float(self & 0xffff0000u);
    const int beg = row_ptr[node], end = row_ptr[node + 1];
    for (int e = beg; e < end; e += 16) {
        int s[16];
        s[0] = csr_src[e];
#pragma unroll
        for (int i = 1; i < 16; ++i)
            s[i] = (e + i < end) ? csr_src[e + i] : s[0];
        unsigned int v[16];
#pragma unroll
        for (int i = 0; i < 16; ++i)
            v[i] = xw[(size_t)s[i] * 64 + lane];
        accx += __uint_as_float(v[0] << 16);
        accy += __uint_as_float(v[0] & 0xffff0000u);
#pragma unroll
        for (int i = 1; i < 16; ++i) {
            if (e + i < end) {
                accx += __uint_as_float(v[i] << 16);
                accy += __uint_as_float(v[i] & 0xffff0000u);
            }
        }
    }
    const float di = dinv[node];
    float2 bv = b2p[lane];
    float v0 = accx * di + bv.x;
    float v1 = accy * di + bv.y;
    float2 o = make_float2(v0 > 0.f ? v0 : 0.f, v1 > 0.f ? v1 : 0.f);
    *(float2*)&h[(size_t)node * 128 + lane * 2] = o;
}

// ---------------- agg2 + mean-pool: F=64 bf16 in, LDS-combined atomics ----------------
__global__ __launch_bounds__(256) void agg2_pool_kernel(const ushort* __restrict__ xw,
                                                        const int* __restrict__ csr_src,
                                                        const int* __restrict__ row_ptr,
                                                        const float* __restrict__ dinv,
                                                        const float* __restrict__ bias,
                                                        const int* __restrict__ batch,
                                                        float* __restrict__ gsum,
                                                        float* __restrict__ gcnt) {
    __shared__ float part[4][64];
    __shared__ int bsh[4];
    const int w = threadIdx.x >> 6;
    const int node = blockIdx.x * 4 + w;
    const int lane = threadIdx.x & 63;
    float acc = __uint_as_float((unsigned int)xw[(size_t)node * 64 + lane] << 16);
    const int beg = row_ptr[node], end = row_ptr[node + 1];
    for (int e = beg; e < end; e += 16) {
        int s[16];
        s[0] = csr_src[e];
#pragma unroll
        for (int i = 1; i < 16; ++i)
            s[i] = (e + i < end) ? csr_src[e + i] : s[0];
        ushort v[16];
#pragma unroll
        for (int i = 0; i < 16; ++i)
            v[i] = xw[(size_t)s[i] * 64 + lane];
        acc += __uint_as_float((unsigned int)v[0] << 16);
#pragma unroll
        for (int i = 1; i < 16; ++i) {
            if (e + i < end) acc += __uint_as_float((unsigned int)v[i] << 16);
        }
    }
    float val = acc * dinv[node] + bias[lane];
    part[w][lane] = val;
    if (lane == 0) bsh[w] = batch[node];
    __syncthreads();
    if (w == 0) {
        int b0 = bsh[0], b1 = bsh[1], b2 = bsh[2], b3 = bsh[3];
        if (b0 == b1 && b1 == b2 && b2 == b3) {
            float s = part[0][lane] + part[1][lane] + part[2][lane] + part[3][lane];
            atomicAdd(&gsum[b0 * 64 + lane], s);
            if (lane == 0) atomicAdd(&gcnt[b0], 4.0f);
        } else {
            atomicAdd(&gsum[b0 * 64 + lane], part[0][lane]);
            atomicAdd(&gsum[b1 * 64 + lane], part[1][lane]);
            atomicAdd(&gsum[b2 * 64 + lane], part[2][lane]);
            atomicAdd(&gsum[b3 * 64 + lane], part[3][lane]);
            if (lane == 0) {
                atomicAdd(&gcnt[b0], 1.0f);
                atomicAdd(&gcnt[b1], 1.0f);
                atomicAdd(&gcnt[b2], 1.0f);
                atomicAdd(&gcnt[b3], 1.0f);
            }
        }
    }
}

// ---------------- head: mean -> fc -> log_softmax ----------------
__global__ void head_kernel(const float* __restrict__ gsum, const float* __restrict__ gcnt,
                            const float* __restrict__ fcW, const float* __restrict__ fcb,
                            float* __restrict__ out) {
    int g = blockIdx.x * blockDim.x + threadIdx.x;
    if (g >= NUM_GRAPHS) return;
    float c = gcnt[g];
    c = c > 1.f ? c : 1.f;
    float inv = 1.f / c;
    float logits[4];
#pragma unroll
    for (int j = 0; j < 4; ++j) logits[j] = fcb[j];
    for (int k = 0; k < 64; ++k) {
        float m = gsum[g * 64 + k] * inv;
#pragma unroll
        for (int j = 0; j < 4; ++j) logits[j] += m * fcW[k * 4 + j];
    }
    float mx = logits[0];
#pragma unroll
    for (int j = 1; j < 4; ++j) mx = logits[j] > mx ? logits[j] : mx;
    float s = 0.f;
#pragma unroll
    for (int j = 0; j < 4; ++j) s += expf(logits[j] - mx);
    float lse = mx + logf(s);
#pragma unroll
    for (int j = 0; j < 4; ++j) out[g * 4 + j] = logits[j] - lse;
}

extern "C" void kernel_launch(void* const* d_in, const int* in_sizes, int n_in,
                              void* d_out, int out_size, void* d_ws, size_t ws_size,
                              hipStream_t stream) {
    const float* x     = (const float*)d_in[0];
    const int*   ei    = (const int*)d_in[1];     // [2, E]
    const int*   batch = (const int*)d_in[2];
    const float* W1    = (const float*)d_in[3];
    const float* b1    = (const float*)d_in[4];
    const float* W2    = (const float*)d_in[5];
    const float* b2    = (const float*)d_in[6];
    const float* fcW   = (const float*)d_in[7];
    const float* fcb   = (const float*)d_in[8];
    float* out = (float*)d_out;

    const int* src = ei;
    const int* dst = ei + N_EDGES;

    size_t o = 0;
    char* wsb = (char*)d_ws;
    auto take = [&](size_t bytes) -> void* {
        void* p = wsb + o;
        o += (bytes + 255) & ~(size_t)255;
        return p;
    };
    int*   cnt       = (int*)take((size_t)N_NODES * 4);
    float* dinv      = (float*)take((size_t)N_NODES * 4);
    int*   row_ptr   = (int*)take((size_t)(N_NODES + 1) * 4);
    int*   bcursor   = (int*)take((size_t)NBUCKETS * 4);
    int*   csr_src   = (int*)take((size_t)N_EDGES * 4);
    int2*  pairs     = (int2*)take((size_t)N_EDGES * 8);
    int*   blockSums = (int*)take(1024);
    ushort* W1t      = (ushort*)take((size_t)128 * 256 * 2);
    ushort* bufA     = (ushort*)take((size_t)N_NODES * 128 * 2);  // bf16 xw1'/xw2'
    float* bufB      = (float*)take((size_t)N_NODES * 128 * 4);   // h1 (fp32)
    float* gsum      = (float*)take((size_t)NUM_GRAPHS * 64 * 4);
    float* gcnt      = (float*)take((size_t)NUM_GRAPHS * 4);
    (void)ws_size;

    const int TB = 256;

    zero_i32_kernel<<<(N_NODES + TB - 1) / TB, TB, 0, stream>>>(cnt, N_NODES);
    zero_i32_kernel<<<(NUM_GRAPHS * 64 + TB - 1) / TB, TB, 0, stream>>>((int*)gsum, NUM_GRAPHS * 64);
    zero_i32_kernel<<<(NUM_GRAPHS + TB - 1) / TB, TB, 0, stream>>>((int*)gcnt, NUM_GRAPHS);

    prep_w1t_kernel<<<128, TB, 0, stream>>>(W1, W1t);

    count_dst_kernel<<<(N_EDGES + TB - 1) / TB, TB, 0, stream>>>(dst, cnt);
    dinv_kernel<<<(N_NODES + TB - 1) / TB, TB, 0, stream>>>(cnt, dinv);

    scan1_kernel<<<SCAN_NB, SCAN_B, 0, stream>>>(cnt, row_ptr, blockSums);
    scan2_kernel<<<1, 128, 0, stream>>>(blockSums, row_ptr);
    scan3_kernel<<<(N_NODES + TB - 1) / TB, TB, 0, stream>>>(row_ptr, blockSums, bcursor);

    // fused: gemm1 (bf16 MFMA) + edge binning
    gemm1_fill_kernel<<<FUSED_BLOCKS, TB, 0, stream>>>(x, W1t, dinv, bufA,
                                                       src, dst, bcursor, pairs);

    csr_fill_local_kernel<<<NBUCKETS, TB, 0, stream>>>(pairs, row_ptr, csr_src);

    agg1_kernel<<<N_NODES / 4, TB, 0, stream>>>((const unsigned int*)bufA, csr_src, row_ptr,
                                                dinv, b1, bufB);

    gemm2_kernel<<<(N_NODES + 127) / 128, TB, 0, stream>>>(bufB, W2, dinv, bufA);
    agg2_pool_kernel<<<N_NODES / 4, TB, 0, stream>>>(bufA, csr_src, row_ptr, dinv, b2, batch,
                                                     gsum, gcnt);

    head_kernel<<<(NUM_GRAPHS + TB - 1) / TB, TB, 0, stream>>>(gsum, gcnt, fcW, fcb, out);
}

// Round 7
// 436.543 us; speedup vs baseline: 2.9741x; 1.1331x over previous
//
#include <hip/hip_runtime.h>
#include <hip/hip_bf16.h>

#define N_NODES 100000
#define N_EDGES 1600000
#define NUM_GRAPHS 1000
#define SCAN_B 1024
#define SCAN_NB ((N_NODES + SCAN_B - 1) / SCAN_B)   // 98

#define NODES_PER_BUCKET 256
#define BUCKET_SHIFT 8
#define NBUCKETS 391                                 // ceil(100000/256)

#define G1_BLOCKS 1563            // 100000/64
#define FUSED_BLOCKS 1759         // b%9==4 -> bin (195), else gemm (1564, last guarded)
#define FILL_CHUNK 8206           // ceil(1.6M/195)

typedef __attribute__((ext_vector_type(8))) short short8;
typedef __attribute__((ext_vector_type(4))) float f32x4;
typedef unsigned short ushort;

__device__ __forceinline__ ushort f2bf(float f) {
    unsigned int u = __float_as_uint(f);
    u = u + 0x7fffu + ((u >> 16) & 1u);      // round-to-nearest-even
    return (ushort)(u >> 16);
}
__device__ __forceinline__ float bflo(unsigned int u) { return __uint_as_float(u << 16); }
__device__ __forceinline__ float bfhi(unsigned int u) { return __uint_as_float(u & 0xffff0000u); }

// ---------------- fused setup: zero cnt, W1^T bf16, W2^T bf16, zero gsum/gcnt ----------------
__global__ void setup_kernel(int* __restrict__ cnt,
                             const float* __restrict__ W1, ushort* __restrict__ W1t,
                             const float* __restrict__ W2, ushort* __restrict__ W2t,
                             float* __restrict__ gsum, float* __restrict__ gcnt) {
    int b = blockIdx.x, tid = threadIdx.x;
    if (b < 391) {
        int i = b * 256 + tid;
        if (i < N_NODES) cnt[i] = 0;
    } else if (b < 519) {
        int idx = (b - 391) * 256 + tid;             // 32768
        int n = idx & 127, k = idx >> 7;
        W1t[n * 256 + k] = f2bf(W1[k * 128 + n]);
    } else if (b < 551) {
        int idx = (b - 519) * 256 + tid;             // 8192
        int n = idx & 63, k = idx >> 6;
        W2t[n * 128 + k] = f2bf(W2[k * 64 + n]);
    } else {
        int idx = (b - 551) * 256 + tid;
        if (idx < NUM_GRAPHS * 64) gsum[idx] = 0.f;
        else if (idx < NUM_GRAPHS * 64 + NUM_GRAPHS) gcnt[idx - NUM_GRAPHS * 64] = 0.f;
    }
}
#define SETUP_BLOCKS 805

// ---------------- degree / dinv ----------------
__global__ void count_dst_kernel(const int* __restrict__ dst, int* __restrict__ cnt) {
    int e = blockIdx.x * blockDim.x + threadIdx.x;
    if (e < N_EDGES) atomicAdd(&cnt[dst[e]], 1);
}

__global__ void dinv_kernel(const int* __restrict__ cnt, float* __restrict__ dinv) {
    int i = blockIdx.x * blockDim.x + threadIdx.x;
    if (i < N_NODES) dinv[i] = rsqrtf((float)(cnt[i] + 1));  // +1 self loop
}

// ---------------- exclusive scan (row_ptr) ----------------
__global__ void scan1_kernel(const int* __restrict__ cnt, int* __restrict__ row_ptr,
                             int* __restrict__ blockSums) {
    __shared__ int sh[SCAN_B];
    int t = threadIdx.x;
    int i = blockIdx.x * SCAN_B + t;
    int v = (i < N_NODES) ? cnt[i] : 0;
    sh[t] = v;
    for (int off = 1; off < SCAN_B; off <<= 1) {
        __syncthreads();
        int add = (t >= off) ? sh[t - off] : 0;
        __syncthreads();
        sh[t] += add;
    }
    if (i < N_NODES) row_ptr[i] = sh[t] - v;
    if (t == SCAN_B - 1) blockSums[blockIdx.x] = sh[t];
}

__global__ void scan2_kernel(int* __restrict__ blockSums, int* __restrict__ row_ptr) {
    __shared__ int sh[128];
    int t = threadIdx.x;
    int v = (t < SCAN_NB) ? blockSums[t] : 0;
    sh[t] = v;
    for (int off = 1; off < 128; off <<= 1) {
        __syncthreads();
        int add = (t >= off) ? sh[t - off] : 0;
        __syncthreads();
        sh[t] += add;
    }
    __syncthreads();
    if (t < SCAN_NB) blockSums[t] = sh[t] - v;
    if (t == SCAN_NB - 1) row_ptr[N_NODES] = sh[t];
}

__global__ void scan3_kernel(int* __restrict__ row_ptr, const int* __restrict__ blockSums,
                             int* __restrict__ bcursor) {
    int i = blockIdx.x * blockDim.x + threadIdx.x;
    if (i < N_NODES) {
        int v = row_ptr[i] + blockSums[i / SCAN_B];
        row_ptr[i] = v;
        if ((i & (NODES_PER_BUCKET - 1)) == 0) bcursor[i >> BUCKET_SHIFT] = v;
    }
}

// ---------------- fused: GEMM1 via bf16 MFMA + edge binning ----------------
__global__ __launch_bounds__(256) void gemm1_fill_kernel(const float* __restrict__ x,
                                                         const ushort* __restrict__ W1t,
                                                         const float* __restrict__ dinv,
                                                         ushort* __restrict__ outb,
                                                         const int* __restrict__ esrc,
                                                         const int* __restrict__ edst,
                                                         int* __restrict__ bcursor,
                                                         int2* __restrict__ pairs) {
    __shared__ ushort Ab[64 * 32];    // 4 KB
    __shared__ ushort Bb[128 * 32];   // 8 KB
    const int b = blockIdx.x;
    const int tid = threadIdx.x;

    if (b % 9 == 4) {
        // ---- bin role ----
        int* scnt = (int*)Ab;
        int* spos = (int*)Bb;
        const int fid = b / 9;
        const int beg = fid * FILL_CHUNK;
        int end = beg + FILL_CHUNK;
        if (end > N_EDGES) end = N_EDGES;
        for (int i = tid; i < NBUCKETS; i += 256) scnt[i] = 0;
        __syncthreads();
        for (int e = beg + tid; e < end; e += 256)
            atomicAdd(&scnt[edst[e] >> BUCKET_SHIFT], 1);
        __syncthreads();
        for (int i = tid; i < NBUCKETS; i += 256) {
            int c = scnt[i];
            spos[i] = c > 0 ? atomicAdd(&bcursor[i], c) : 0;
        }
        __syncthreads();
        for (int e = beg + tid; e < end; e += 256) {
            int d = edst[e];
            int s = esrc[e];
            int p = atomicAdd(&spos[d >> BUCKET_SHIFT], 1);
            pairs[p] = make_int2(s, d);
        }
        return;
    }

    // ---- GEMM role (MFMA) ----
    const int gid = b - (b + 4) / 9;
    if (gid >= G1_BLOCKS) return;
    const int row0 = gid * 64;
    const int wv = tid >> 6;
    const int l = tid & 63;
    const int lrow = l & 15;
    const int quad = l >> 4;

    const int ar = tid >> 2;
    const int ak = (tid & 3) * 8;
    int grow = row0 + ar;
    if (grow > N_NODES - 1) grow = N_NODES - 1;
    const float* xrow = x + (size_t)grow * 256;
    const int bn = tid >> 1;
    const int bk = (tid & 1) * 16;

    f32x4 acc[8];
#pragma unroll
    for (int t = 0; t < 8; ++t) acc[t] = (f32x4){0.f, 0.f, 0.f, 0.f};

    for (int kc = 0; kc < 8; ++kc) {
        float4 a0 = *(const float4*)&xrow[kc * 32 + ak];
        float4 a1 = *(const float4*)&xrow[kc * 32 + ak + 4];
        const ushort* wt = &W1t[(size_t)bn * 256 + kc * 32 + bk];
        uint4 w0 = *(const uint4*)wt;
        uint4 w1 = *(const uint4*)(wt + 8);

        if (kc > 0) __syncthreads();
        ushort av[8];
        av[0] = f2bf(a0.x); av[1] = f2bf(a0.y); av[2] = f2bf(a0.z); av[3] = f2bf(a0.w);
        av[4] = f2bf(a1.x); av[5] = f2bf(a1.y); av[6] = f2bf(a1.z); av[7] = f2bf(a1.w);
        *(uint4*)&Ab[ar * 32 + ak] = *(uint4*)av;
        *(uint4*)&Bb[bn * 32 + bk] = w0;
        *(uint4*)&Bb[bn * 32 + bk + 8] = w1;
        __syncthreads();

        short8 afrag = *(const short8*)&Ab[(wv * 16 + lrow) * 32 + quad * 8];
#pragma unroll
        for (int t = 0; t < 8; ++t) {
            short8 bfrag = *(const short8*)&Bb[(t * 16 + lrow) * 32 + quad * 8];
            acc[t] = __builtin_amdgcn_mfma_f32_16x16x32_bf16(afrag, bfrag, acc[t], 0, 0, 0);
        }
    }

    const int rbase = row0 + wv * 16 + quad * 4;
    float dv[4];
#pragma unroll
    for (int r = 0; r < 4; ++r) {
        int rr = rbase + r;
        dv[r] = (rr < N_NODES) ? dinv[rr] : 0.f;
    }
#pragma unroll
    for (int t = 0; t < 8; ++t) {
#pragma unroll
        for (int r = 0; r < 4; ++r) {
            int row = rbase + r;
            if (row < N_NODES)
                outb[(size_t)row * 128 + t * 16 + lrow] = f2bf(acc[t][r] * dv[r]);
        }
    }
}

// ---------------- per-bucket local CSR fill ----------------
__global__ __launch_bounds__(256) void csr_fill_local_kernel(const int2* __restrict__ pairs,
                                                             const int* __restrict__ row_ptr,
                                                             int* __restrict__ csr_src) {
    __shared__ int cur[NODES_PER_BUCKET];
    const int b = blockIdx.x;
    const int n0 = b * NODES_PER_BUCKET;
    int n1 = n0 + NODES_PER_BUCKET;
    if (n1 > N_NODES) n1 = N_NODES;
    const int tid = threadIdx.x;
    for (int i = tid; i < n1 - n0; i += 256) cur[i] = row_ptr[n0 + i];
    __syncthreads();
    const int pbeg = row_ptr[n0];
    const int pend = row_ptr[n1];
    for (int p = pbeg + tid; p < pend; p += 256) {
        int2 pr = pairs[p];
        int pos = atomicAdd(&cur[pr.y - n0], 1);
        csr_src[pos] = pr.x;
    }
}

// ---------------- agg1: h(bf16) = relu(dinv .* sum(bf16 xw' rows) + b1); F=128 ----------------
// 2 nodes per wave: half-wave h2 = lane>>5 -> node; lane&31 covers 8 B (4 bf16).
__global__ __launch_bounds__(256) void agg1_kernel(const uint2* __restrict__ xw,   // [N][32]
                                                   const int* __restrict__ csr_src,
                                                   const int* __restrict__ row_ptr,
                                                   const float* __restrict__ dinv,
                                                   const float* __restrict__ bias,
                                                   ushort* __restrict__ h) {      // bf16 [N][128]
    const int wave = threadIdx.x >> 6;
    const int lane = threadIdx.x & 63;
    const int h2 = lane >> 5;
    const int c = lane & 31;
    const int node = blockIdx.x * 8 + wave * 2 + h2;

    uint2 sv = xw[(size_t)node * 32 + c];
    float a0 = bflo(sv.x), a1 = bfhi(sv.x), a2 = bflo(sv.y), a3 = bfhi(sv.y);

    const int beg = row_ptr[node], end = row_ptr[node + 1];
    for (int e = beg; e < end; e += 16) {
        int s[16];
        s[0] = csr_src[e];
#pragma unroll
        for (int i = 1; i < 16; ++i)
            s[i] = (e + i < end) ? csr_src[e + i] : s[0];
        uint2 v[16];
#pragma unroll
        for (int i = 0; i < 16; ++i)
            v[i] = xw[(size_t)s[i] * 32 + c];
        a0 += bflo(v[0].x); a1 += bfhi(v[0].x); a2 += bflo(v[0].y); a3 += bfhi(v[0].y);
#pragma unroll
        for (int i = 1; i < 16; ++i) {
            if (e + i < end) {
                a0 += bflo(v[i].x); a1 += bfhi(v[i].x);
                a2 += bflo(v[i].y); a3 += bfhi(v[i].y);
            }
        }
    }
    const float di = dinv[node];
    float4 bv = *(const float4*)&bias[c * 4];
    float v0 = a0 * di + bv.x, v1 = a1 * di + bv.y;
    float v2 = a2 * di + bv.z, v3 = a3 * di + bv.w;
    ushort4 o;
    o.x = f2bf(v0 > 0.f ? v0 : 0.f);
    o.y = f2bf(v1 > 0.f ? v1 : 0.f);
    o.z = f2bf(v2 > 0.f ? v2 : 0.f);
    o.w = f2bf(v3 > 0.f ? v3 : 0.f);
    *(ushort4*)&h[(size_t)node * 128 + c * 4] = o;
}

// ---------------- GEMM2 via bf16 MFMA: outb = bf16(dinv[r] * (h @ W2)) ----------------
// h bf16 [N][128], W2t bf16 [64][128]; 64 rows x 64 cols per block.
__global__ __launch_bounds__(256) void gemm2_kernel(const ushort* __restrict__ h,
                                                    const ushort* __restrict__ W2t,
                                                    const float* __restrict__ dinv,
                                                    ushort* __restrict__ outb) {
    __shared__ ushort Ab[64 * 32];   // 4 KB
    __shared__ ushort Bb[64 * 32];   // 4 KB
    const int tid = threadIdx.x;
    const int row0 = blockIdx.x * 64;
    const int wv = tid >> 6;
    const int l = tid & 63;
    const int lrow = l & 15;
    const int quad = l >> 4;

    const int ar = tid >> 2;
    const int ak = (tid & 3) * 8;
    int grow = row0 + ar;
    if (grow > N_NODES - 1) grow = N_NODES - 1;

    f32x4 acc[4];
#pragma unroll
    for (int t = 0; t < 4; ++t) acc[t] = (f32x4){0.f, 0.f, 0.f, 0.f};

    for (int kc = 0; kc < 4; ++kc) {
        uint4 a = *(const uint4*)&h[(size_t)grow * 128 + kc * 32 + ak];
        uint4 w = *(const uint4*)&W2t[(size_t)ar * 128 + kc * 32 + ak];
        if (kc > 0) __syncthreads();
        *(uint4*)&Ab[ar * 32 + ak] = a;
        *(uint4*)&Bb[ar * 32 + ak] = w;
        __syncthreads();

        short8 afrag = *(const short8*)&Ab[(wv * 16 + lrow) * 32 + quad * 8];
#pragma unroll
        for (int t = 0; t < 4; ++t) {
            short8 bfrag = *(const short8*)&Bb[(t * 16 + lrow) * 32 + quad * 8];
            acc[t] = __builtin_amdgcn_mfma_f32_16x16x32_bf16(afrag, bfrag, acc[t], 0, 0, 0);
        }
    }

    const int rbase = row0 + wv * 16 + quad * 4;
#pragma unroll
    for (int r = 0; r < 4; ++r) {
        int row = rbase + r;
        if (row < N_NODES) {
            float dv = dinv[row];
#pragma unroll
            for (int t = 0; t < 4; ++t)
                outb[(size_t)row * 64 + t * 16 + lrow] = f2bf(acc[t][r] * dv);
        }
    }
}

// ---------------- agg2 + mean-pool: F=64 bf16, 4 nodes/wave, LDS-combined atomics ----------------
__global__ __launch_bounds__(256) void agg2_pool_kernel(const uint2* __restrict__ xw,  // [N][16]
                                                        const int* __restrict__ csr_src,
                                                        const int* __restrict__ row_ptr,
                                                        const float* __restrict__ dinv,
                                                        const float* __restrict__ bias,
                                                        const int* __restrict__ batch,
                                                        float* __restrict__ gsum,
                                                        float* __restrict__ gcnt) {
    __shared__ float part[16][64];
    __shared__ int bsh[16];
    const int wave = threadIdx.x >> 6;
    const int lane = threadIdx.x & 63;
    const int q = lane >> 4;
    const int c = lane & 15;
    const int nl = wave * 4 + q;                 // local node 0..15
    const int node = blockIdx.x * 16 + nl;

    uint2 sv = xw[(size_t)node * 16 + c];
    float a0 = bflo(sv.x), a1 = bfhi(sv.x), a2 = bflo(sv.y), a3 = bfhi(sv.y);

    const int beg = row_ptr[node], end = row_ptr[node + 1];
    for (int e = beg; e < end; e += 16) {
        int s[16];
        s[0] = csr_src[e];
#pragma unroll
        for (int i = 1; i < 16; ++i)
            s[i] = (e + i < end) ? csr_src[e + i] : s[0];
        uint2 v[16];
#pragma unroll
        for (int i = 0; i < 16; ++i)
            v[i] = xw[(size_t)s[i] * 16 + c];
        a0 += bflo(v[0].x); a1 += bfhi(v[0].x); a2 += bflo(v[0].y); a3 += bfhi(v[0].y);
#pragma unroll
        for (int i = 1; i < 16; ++i) {
            if (e + i < end) {
                a0 += bflo(v[i].x); a1 += bfhi(v[i].x);
                a2 += bflo(v[i].y); a3 += bfhi(v[i].y);
            }
        }
    }
    const float di = dinv[node];
    float4 bv = *(const float4*)&bias[c * 4];
    float4 val = make_float4(a0 * di + bv.x, a1 * di + bv.y, a2 * di + bv.z, a3 * di + bv.w);
    *(float4*)&part[nl][c * 4] = val;
    if (lane == (q << 4)) bsh[nl] = batch[node];
    __syncthreads();

    if (wave == 0) {
        int b0 = bsh[0];
        bool same = true;
#pragma unroll
        for (int i = 1; i < 16; ++i) same = same && (bsh[i] == b0);
        if (same) {
            float s = 0.f;
#pragma unroll
            for (int i = 0; i < 16; ++i) s += part[i][lane];
            atomicAdd(&gsum[b0 * 64 + lane], s);
            if (lane == 0) atomicAdd(&gcnt[b0], 16.0f);
        } else {
#pragma unroll
            for (int i = 0; i < 16; ++i)
                atomicAdd(&gsum[bsh[i] * 64 + lane], part[i][lane]);
            if (lane == 0) {
#pragma unroll
                for (int i = 0; i < 16; ++i) atomicAdd(&gcnt[bsh[i]], 1.0f);
            }
        }
    }
}

// ---------------- head: mean -> fc -> log_softmax ----------------
__global__ void head_kernel(const float* __restrict__ gsum, const float* __restrict__ gcnt,
                            const float* __restrict__ fcW, const float* __restrict__ fcb,
                            float* __restrict__ out) {
    int g = blockIdx.x * blockDim.x + threadIdx.x;
    if (g >= NUM_GRAPHS) return;
    float c = gcnt[g];
    c = c > 1.f ? c : 1.f;
    float inv = 1.f / c;
    float logits[4];
#pragma unroll
    for (int j = 0; j < 4; ++j) logits[j] = fcb[j];
    for (int k = 0; k < 64; ++k) {
        float m = gsum[g * 64 + k] * inv;
#pragma unroll
        for (int j = 0; j < 4; ++j) logits[j] += m * fcW[k * 4 + j];
    }
    float mx = logits[0];
#pragma unroll
    for (int j = 1; j < 4; ++j) mx = logits[j] > mx ? logits[j] : mx;
    float s = 0.f;
#pragma unroll
    for (int j = 0; j < 4; ++j) s += expf(logits[j] - mx);
    float lse = mx + logf(s);
#pragma unroll
    for (int j = 0; j < 4; ++j) out[g * 4 + j] = logits[j] - lse;
}

extern "C" void kernel_launch(void* const* d_in, const int* in_sizes, int n_in,
                              void* d_out, int out_size, void* d_ws, size_t ws_size,
                              hipStream_t stream) {
    const float* x     = (const float*)d_in[0];
    const int*   ei    = (const int*)d_in[1];     // [2, E]
    const int*   batch = (const int*)d_in[2];
    const float* W1    = (const float*)d_in[3];
    const float* b1    = (const float*)d_in[4];
    const float* W2    = (const float*)d_in[5];
    const float* b2    = (const float*)d_in[6];
    const float* fcW   = (const float*)d_in[7];
    const float* fcb   = (const float*)d_in[8];
    float* out = (float*)d_out;

    const int* src = ei;
    const int* dst = ei + N_EDGES;

    size_t o = 0;
    char* wsb = (char*)d_ws;
    auto take = [&](size_t bytes) -> void* {
        void* p = wsb + o;
        o += (bytes + 255) & ~(size_t)255;
        return p;
    };
    int*   cnt       = (int*)take((size_t)N_NODES * 4);
    float* dinv      = (float*)take((size_t)N_NODES * 4);
    int*   row_ptr   = (int*)take((size_t)(N_NODES + 1) * 4);
    int*   bcursor   = (int*)take((size_t)NBUCKETS * 4);
    int*   csr_src   = (int*)take((size_t)N_EDGES * 4);
    int2*  pairs     = (int2*)take((size_t)N_EDGES * 8);
    int*   blockSums = (int*)take(1024);
    ushort* W1t      = (ushort*)take((size_t)128 * 256 * 2);
    ushort* W2t      = (ushort*)take((size_t)64 * 128 * 2);
    ushort* bufA     = (ushort*)take((size_t)N_NODES * 128 * 2);  // bf16 xw1'/xw2'
    ushort* bufB     = (ushort*)take((size_t)N_NODES * 128 * 2);  // h1 (bf16)
    float* gsum      = (float*)take((size_t)NUM_GRAPHS * 64 * 4);
    float* gcnt      = (float*)take((size_t)NUM_GRAPHS * 4);
    (void)ws_size;

    const int TB = 256;

    setup_kernel<<<SETUP_BLOCKS, TB, 0, stream>>>(cnt, W1, W1t, W2, W2t, gsum, gcnt);

    count_dst_kernel<<<(N_EDGES + TB - 1) / TB, TB, 0, stream>>>(dst, cnt);
    dinv_kernel<<<(N_NODES + TB - 1) / TB, TB, 0, stream>>>(cnt, dinv);

    scan1_kernel<<<SCAN_NB, SCAN_B, 0, stream>>>(cnt, row_ptr, blockSums);
    scan2_kernel<<<1, 128, 0, stream>>>(blockSums, row_ptr);
    scan3_kernel<<<(N_NODES + TB - 1) / TB, TB, 0, stream>>>(row_ptr, blockSums, bcursor);

    gemm1_fill_kernel<<<FUSED_BLOCKS, TB, 0, stream>>>(x, W1t, dinv, bufA,
                                                       src, dst, bcursor, pairs);

    csr_fill_local_kernel<<<NBUCKETS, TB, 0, stream>>>(pairs, row_ptr, csr_src);

    agg1_kernel<<<N_NODES / 8, TB, 0, stream>>>((const uint2*)bufA, csr_src, row_ptr,
                                                dinv, b1, bufB);

    gemm2_kernel<<<(N_NODES + 63) / 64, TB, 0, stream>>>(bufB, W2t, dinv, bufA);

    agg2_pool_kernel<<<N_NODES / 16, TB, 0, stream>>>((const uint2*)bufA, csr_src, row_ptr,
                                                      dinv, b2, batch, gsum, gcnt);

    head_kernel<<<(NUM_GRAPHS + TB - 1) / TB, TB, 0, stream>>>(gsum, gcnt, fcW, fcb, out);
}